// Round 5
// baseline (433.800 us; speedup 1.0000x reference)
//
#include <hip/hip_runtime.h>
#include <hip/hip_bf16.h>
#include <math.h>

typedef __bf16 bf16_t;
typedef __bf16 bf16x8 __attribute__((ext_vector_type(8)));
typedef __bf16 bf16x4 __attribute__((ext_vector_type(4)));
typedef float f32x4 __attribute__((ext_vector_type(4)));

// ---------- async global->LDS (16B per lane), wave-uniform base + lane*16 ----------
__device__ __forceinline__ void async_ld16(const void* g, void* l) {
  __builtin_amdgcn_global_load_lds(
      (const __attribute__((address_space(1))) unsigned int*)g,
      (__attribute__((address_space(3))) unsigned int*)l, 16, 0, 0);
}

// ---------- problem constants ----------
#define BATCH 2
#define SEQ   8192
#define EMB   768
#define NHEAD 12
#define HD    64
#define TOK   (BATCH*SEQ)          // 16384
#define GATH_PER_B 57344           // sum over heads of L_h = 4*(8192+4096+2048)

// group of head h: g = h>>2 ; L = 8192>>g ; s = 2048<<g ; r = 1<<g ; off = g
__device__ __forceinline__ int headoff(int h) {
  int g = h >> 2;
  int base = (g == 0) ? 0 : ((g == 1) ? 32768 : 49152);
  return base + (h & 3) * (8192 >> g);
}

// exp2 via compiler intrinsic (scores pre-scaled by log2(e) upstream).
__device__ __forceinline__ float fast_exp2(float x) {
#if __has_builtin(__builtin_amdgcn_exp2f)
  return __builtin_amdgcn_exp2f(x);
#else
  return exp2f(x);
#endif
}

// ---------- fp32 -> bf16 cast (8 elems/thread, 16B stores) ----------
__global__ void k_cast(const float* __restrict__ in, bf16_t* __restrict__ out, int n) {
  int i = (blockIdx.x * blockDim.x + threadIdx.x) * 8;
  if (i < n) {
    float4 a = *(const float4*)(in + i);
    float4 b = *(const float4*)(in + i + 4);
    __attribute__((aligned(16))) bf16_t o[8] = {
        (bf16_t)a.x, (bf16_t)a.y, (bf16_t)a.z, (bf16_t)a.w,
        (bf16_t)b.x, (bf16_t)b.y, (bf16_t)b.z, (bf16_t)b.w};
    *(uint4*)(out + i) = *(uint4*)o;
  }
}

// ---------- QKV GEMM: fp32 A staged directly via DMA (cast fused), bf16 W ----------
// A is the RAW fp32 input (query/key/value); fragments convert f32->bf16 in-register
// (same RNE rounding as the old k_cast pass => identical numerics, one less HBM pass).
// A-chunks are XOR-swizzled (slot pc holds logical chunk pc^(row&7)) to keep the
// stride-128B f32 reads at the bf16 path's conflict level.
// 1-D grid of 2304 with XCD-chunked swizzle (8 XCDs x 288): the 6 blocks sharing one
// 128x768 A-panel run consecutively on the same XCD's L2.
__global__ __launch_bounds__(256, 3)
void k_gemm_qkv(const float* __restrict__ qf, const float* __restrict__ kf,
                const float* __restrict__ vf, const bf16_t* __restrict__ wqkv,
                const float* __restrict__ qkv_bias,
                bf16_t* __restrict__ Qg, bf16_t* __restrict__ Kg, bf16_t* __restrict__ Vb) {
  const int N = 768, K = 768;
  int id = blockIdx.x;
  int wid = (id & 7) * 288 + (id >> 3);
  int z = wid / 768;
  int rem = wid - z * 768;
  int ytile = rem / 6;
  int xtile = rem - ytile * 6;
  int m0 = ytile * 128, n0 = xtile * 128;

  const float* A = (z == 0) ? qf : (z == 1) ? kf : vf;
  const bf16_t* W = wqkv + (size_t)z * N * K;
  const float* bias = qkv_bias + z * N;

  __shared__ float  As[2][128][32];   // 32KB: fp32 A tile, chunk-swizzled
  __shared__ bf16_t Bs[2][128][32];   // 16KB

  int tid = threadIdx.x;
  int wave = tid >> 6, lane = tid & 63;
  int q = lane >> 4, c = lane & 15;
  int cx = c & 7;
  int wm = (wave & 1) * 64, wn = (wave >> 1) * 64;

  auto stage = [&](int k0, int bsel) {
    // A: 128 rows x 8 chunks of 16B (4 f32) = 1024 chunks; source swizzled
#pragma unroll
    for (int it = 0; it < 4; ++it) {
      int ch = tid + it * 256;
      int row = ch >> 3, pc = ch & 7, lc = pc ^ (row & 7);
      async_ld16(A + (size_t)(m0 + row) * K + k0 + lc * 4,
                 (float*)&As[bsel][0][0] + ch * 4);
    }
    // W: 128 rows x 4 chunks of 16B (8 bf16) = 512 chunks, linear
#pragma unroll
    for (int it = 0; it < 2; ++it) {
      int ch = tid + it * 256;
      int row = ch >> 2, kb8 = (ch & 3) << 3;
      async_ld16(W + (size_t)(n0 + row) * K + k0 + kb8, &Bs[bsel][row][kb8]);
    }
  };

  f32x4 acc[4][4];
#pragma unroll
  for (int i = 0; i < 4; i++)
#pragma unroll
    for (int j = 0; j < 4; j++) acc[i][j] = (f32x4){0.f, 0.f, 0.f, 0.f};

  int s0 = (q * 2) ^ cx, s1 = (q * 2 + 1) ^ cx;   // physical slots of logical chunks

  stage(0, 0);
#pragma unroll 2
  for (int kt = 0; kt < 24; ++kt) {
    int cur = kt & 1;
    __syncthreads();                    // buf[cur] staged; prior reads of buf[cur^1] done
    if (kt + 1 < 24) stage((kt + 1) * 32, cur ^ 1);
    bf16x8 af[4], bfr[4];
#pragma unroll
    for (int mi = 0; mi < 4; mi++) {
      const float* ar = &As[cur][wm + mi * 16 + c][0];
      f32x4 a0 = *(const f32x4*)(ar + s0 * 4);
      f32x4 a1 = *(const f32x4*)(ar + s1 * 4);
      bf16x8 t;
#pragma unroll
      for (int j = 0; j < 4; j++) { t[j] = (bf16_t)a0[j]; t[4 + j] = (bf16_t)a1[j]; }
      af[mi] = t;
    }
#pragma unroll
    for (int nj = 0; nj < 4; nj++) bfr[nj] = *(const bf16x8*)&Bs[cur][wn + nj * 16 + c][q * 8];
#pragma unroll
    for (int mi = 0; mi < 4; mi++)
#pragma unroll
      for (int nj = 0; nj < 4; nj++)
        acc[mi][nj] = __builtin_amdgcn_mfma_f32_16x16x32_bf16(af[mi], bfr[nj], acc[mi][nj], 0, 0, 0);
  }

  if (z == 2) {
#pragma unroll
    for (int mi = 0; mi < 4; mi++)
#pragma unroll
      for (int nj = 0; nj < 4; nj++)
#pragma unroll
        for (int rg = 0; rg < 4; rg++) {
          int row = m0 + wm + mi * 16 + q * 4 + rg;
          int col = n0 + wn + nj * 16 + c;
          Vb[(size_t)row * N + col] = (bf16_t)(acc[mi][nj][rg] + bias[col]);
        }
  } else {
    bf16_t* dst = (z == 0) ? Qg : Kg;
    // Q pre-scale folds 1/sqrt(64) AND log2(e) so attn can use raw 2^x
    float qscale = (z == 0) ? 0.125f * 1.44269504088896f : 1.0f;
#pragma unroll
    for (int mi = 0; mi < 4; mi++)
#pragma unroll
      for (int nj = 0; nj < 4; nj++) {
        int e = n0 + wn + nj * 16 + c;
        int h = e >> 6, dim = e & 63, g2 = h >> 2;
        int rm1 = (1 << g2) - 1, sh = 11 + g2;
        int smask = (2048 << g2) - 1;
        int ho = headoff(h);
#pragma unroll
        for (int rg = 0; rg < 4; rg++) {
          int row = m0 + wm + mi * 16 + q * 4 + rg;
          float v = (acc[mi][nj][rg] + bias[e]) * qscale;
          int bb = row >> 13, p = row & 8191;
          int t = (p & smask) - g2;           // off == g2
          if (t >= 0 && (t & rm1) == 0) {
            int jj = (p >> sh) * 2048 + (t >> g2);
            dst[(size_t)(bb * GATH_PER_B + ho + jj) * HD + dim] = (bf16_t)v;
          }
        }
      }
  }
}

// ---------- output GEMM: fp32 out (2-phase pipelined, XCD-chunked swizzle) ----------
__global__ __launch_bounds__(256, 4)
void k_gemm_out(const bf16_t* __restrict__ A, const bf16_t* __restrict__ W,
                const float* __restrict__ bias, float* __restrict__ C) {
  const int N = 768, K = 768;
  // 768 blocks = 8 XCDs x 96; work ordered (m-panel, n-tile)
  int id = blockIdx.x;
  int wid = (id & 7) * 96 + (id >> 3);
  int ytile = wid / 6;
  int xtile = wid - ytile * 6;
  int m0 = ytile * 128, n0 = xtile * 128;

  __shared__ bf16_t As[2][128][32];
  __shared__ bf16_t Bs[2][128][32];

  int tid = threadIdx.x;
  int wave = tid >> 6, lane = tid & 63;
  int q = lane >> 4, c = lane & 15;
  int wm = (wave & 1) * 64, wn = (wave >> 1) * 64;

  auto stage = [&](int k0, int bsel) {
#pragma unroll
    for (int it = 0; it < 2; ++it) {
      int ch = tid + it * 256;
      int row = ch >> 2, kb8 = (ch & 3) << 3;
      async_ld16(A + (size_t)(m0 + row) * K + k0 + kb8, &As[bsel][row][kb8]);
      async_ld16(W + (size_t)(n0 + row) * K + k0 + kb8, &Bs[bsel][row][kb8]);
    }
  };

  f32x4 acc[4][4];
#pragma unroll
  for (int i = 0; i < 4; i++)
#pragma unroll
    for (int j = 0; j < 4; j++) acc[i][j] = (f32x4){0.f, 0.f, 0.f, 0.f};

  stage(0, 0);
#pragma unroll 2
  for (int kt = 0; kt < 24; ++kt) {
    int cur = kt & 1;
    __syncthreads();
    if (kt + 1 < 24) stage((kt + 1) * 32, cur ^ 1);
    bf16x8 af[4], bfr[4];
#pragma unroll
    for (int mi = 0; mi < 4; mi++) af[mi] = *(const bf16x8*)&As[cur][wm + mi * 16 + c][q * 8];
#pragma unroll
    for (int nj = 0; nj < 4; nj++) bfr[nj] = *(const bf16x8*)&Bs[cur][wn + nj * 16 + c][q * 8];
#pragma unroll
    for (int mi = 0; mi < 4; mi++)
#pragma unroll
      for (int nj = 0; nj < 4; nj++)
        acc[mi][nj] = __builtin_amdgcn_mfma_f32_16x16x32_bf16(af[mi], bfr[nj], acc[mi][nj], 0, 0, 0);
  }
#pragma unroll
  for (int mi = 0; mi < 4; mi++)
#pragma unroll
    for (int nj = 0; nj < 4; nj++)
#pragma unroll
      for (int rg = 0; rg < 4; rg++) {
        int row = m0 + wm + mi * 16 + q * 4 + rg;
        int col = n0 + wn + nj * 16 + c;
        C[(size_t)row * N + col] = acc[mi][nj][rg] + bias[col];
      }
}

// ---------- V gather: Vb [tok][768] -> Vt [head][dim][L], slot-permuted ----------
__global__ __launch_bounds__(256)
void k_gather_v(const bf16_t* __restrict__ Vb, bf16_t* __restrict__ Vt) {
  int h = blockIdx.y, b = blockIdx.z;
  int g = h >> 2;
  int L = 8192 >> g;
  int jj0 = blockIdx.x * 64;
  if (jj0 >= L) return;
  int s = 2048 << g;
  int hb = b * GATH_PER_B + headoff(h);
  int tid = threadIdx.x;

  __shared__ bf16_t tile[64][72];

#pragma unroll
  for (int it = 0; it < 2; ++it) {
    int ch = tid + it * 256;            // 512 chunks: 64 rows x 8 chunks of 16B
    int rowl = ch >> 3, db = (ch & 7) << 3;
    int jj = jj0 + rowl;
    int p = (jj >> 11) * s + g + ((jj & 2047) << g);
    *(uint4*)&tile[rowl][db] = *(const uint4*)(Vb + ((size_t)(b * SEQ + p)) * EMB + h * HD + db);
  }
  __syncthreads();
  int dim = tid >> 2, sub = tid & 3;
  __attribute__((aligned(16))) bf16_t tmp[16];
#pragma unroll
  for (int sl = 0; sl < 16; sl++) {
    int t = sub * 16 + sl;
    int pos = (t & 3) * 16 + (t >> 2);
    tmp[sl] = tile[pos][dim];
  }
  size_t vdst = ((size_t)hb) * HD + (size_t)dim * L + jj0 + sub * 16;
  *(uint4*)(Vt + vdst) = *(uint4*)&tmp[0];
  *(uint4*)(Vt + vdst + 8) = *(uint4*)&tmp[8];
}

// ---------- flash attention ----------
// Double-buffered K/V staging (80KB LDS, 2 blocks/CU), single barrier per KV tile.
__global__ __launch_bounds__(256, 2)
void k_attn(const bf16_t* __restrict__ Qg, const bf16_t* __restrict__ Kg,
            const bf16_t* __restrict__ Vt, bf16_t* __restrict__ xattn) {
  // block id = qt*56 + seg: all 16 Q-tiles of a segment share an XCD (56 % 8 == 0)
  int u = blockIdx.x;
  int seg = u % 56, qt = u / 56;
  int b = seg / 28, t = seg % 28;
  int g, h, si;
  if (t < 16)      { g = 0; h = t >> 2;              si = t & 3; }
  else if (t < 24) { g = 1; h = 4 + ((t - 16) >> 1); si = (t - 16) & 1; }
  else             { g = 2; h = 8 + (t - 24);        si = 0; }
  int L = 8192 >> g, s = 2048 << g;
  int hb = b * GATH_PER_B + headoff(h);
  int jj0 = si * 2048 + qt * 128;
  int kvbase = si * 2048;

  __shared__ bf16_t Ps[128][64];        // 16KB: P half-tile round-trip; doubles as Q staging
  __shared__ bf16_t Ks[2][128][64];     // 32KB double-buffered
  __shared__ bf16_t Vs[2][64][128];     // 32KB double-buffered ([dim][slot], pre-permuted)

  int tid = threadIdx.x, wave = tid >> 6, lane = tid & 63;
  int q = lane >> 4, c = lane & 15;
  int cx = c & 7;
  int wm = wave * 32;

  auto stageK = [&](int kt, int bsel) {
#pragma unroll
    for (int it = 0; it < 4; ++it) {
      int ch = tid + it * 256;
      int row = ch >> 3, pc = ch & 7, lc = pc ^ (row & 7);
      async_ld16(Kg + ((size_t)(hb + kvbase + kt * 128 + row)) * HD + lc * 8,
                 &Ks[bsel][0][0] + ch * 8);
    }
  };
  auto stageV = [&](int kt, int bsel) {
#pragma unroll
    for (int it = 0; it < 4; ++it) {
      int ch = tid + it * 256;
      int dim = ch >> 4, pc = ch & 15, lc = pc ^ (dim & 7);
      async_ld16(Vt + ((size_t)hb) * HD + (size_t)dim * L + kvbase + kt * 128 + lc * 8,
                 &Vs[bsel][0][0] + ch * 8);
    }
  };

  // stage Q tile [128][64] into Ps area, chunk-swizzled, plus K0/V0 into buffer 0
  bf16_t* Qs = &Ps[0][0];
#pragma unroll
  for (int it = 0; it < 4; ++it) {
    int ch = tid + it * 256;
    int row = ch >> 3, pc = ch & 7, lc = pc ^ (row & 7);
    async_ld16(Qg + ((size_t)(hb + jj0 + row)) * HD + lc * 8, Qs + ch * 8);
  }
  stageK(0, 0);
  stageV(0, 0);
  __syncthreads();                      // Q + K0/V0 staged

  // Q fragments (wave-private Ps rows)
  bf16x8 aq[2][2];
#pragma unroll
  for (int mi = 0; mi < 2; mi++)
#pragma unroll
    for (int kq = 0; kq < 2; kq++) {
      int pch = (kq * 4 + q) ^ cx;
      aq[mi][kq] = *(const bf16x8*)(Qs + (size_t)(wm + mi * 16 + c) * HD + pch * 8);
    }

  float lrow[2][4];
  f32x4 O[2][4];
#pragma unroll
  for (int mi = 0; mi < 2; mi++)
#pragma unroll
    for (int rg = 0; rg < 4; rg++) lrow[mi][rg] = 0.f;
#pragma unroll
  for (int mi = 0; mi < 2; mi++)
#pragma unroll
    for (int vd = 0; vd < 4; vd++) O[mi][vd] = (f32x4){0.f, 0.f, 0.f, 0.f};

#pragma unroll 2
  for (int kt = 0; kt < 16; ++kt) {
    int cur = kt & 1;
    // issue next tile's staging before compute: latency hides under this tile's work
    if (kt < 15) {
      stageK(kt + 1, cur ^ 1);
      stageV(kt + 1, cur ^ 1);
    }

    // S = Q K^T  (Q pre-scaled by log2e/8; scores are in log2 domain)
    f32x4 Sv[2][8];
#pragma unroll
    for (int mi = 0; mi < 2; mi++)
#pragma unroll
      for (int nj = 0; nj < 8; nj++) Sv[mi][nj] = (f32x4){0.f, 0.f, 0.f, 0.f};
#pragma unroll
    for (int kq = 0; kq < 2; kq++) {
      int pch = (kq * 4 + q) ^ cx;
      bf16x8 bk[8];
#pragma unroll
      for (int nj = 0; nj < 8; nj++) bk[nj] = *(const bf16x8*)&Ks[cur][nj * 16 + c][pch * 8];
#pragma unroll
      for (int mi = 0; mi < 2; mi++)
#pragma unroll
        for (int nj = 0; nj < 8; nj++)
          Sv[mi][nj] = __builtin_amdgcn_mfma_f32_16x16x32_bf16(aq[mi][kq], bk[nj], Sv[mi][nj], 0, 0, 0);
    }

    // two KV halves of 64: exp2+pack 4 vals -> ds_write_b64 into Ps[128][64]; then PV
#pragma unroll
    for (int half = 0; half < 2; ++half) {
#pragma unroll
      for (int mi = 0; mi < 2; mi++)
#pragma unroll
        for (int rg = 0; rg < 4; rg++) {
          bf16x4 p4;
          float rs = 0.f;
#pragma unroll
          for (int j = 0; j < 4; j++) {
            float p = fast_exp2(Sv[mi][half * 4 + j][rg]);
            rs += p;
            p4[j] = (bf16_t)p;
          }
          lrow[mi][rg] += rs;
          int row = wm + mi * 16 + q * 4 + rg;
          int u8 = c ^ ((row & 7) << 1);          // 8B-unit swizzle
          *(bf16x4*)((char*)&Ps[row][0] + u8 * 8) = p4;
        }
      // no barrier: Ps rows wm..wm+31 wave-private (DS ops in-order within a wave)
#pragma unroll
      for (int kk2 = 0; kk2 < 2; ++kk2) {
        bf16x8 ap[2], bv[4];
#pragma unroll
        for (int mi = 0; mi < 2; mi++) {
          int u8 = (kk2 * 8 + q * 2) ^ (cx << 1); // even: b128-aligned
          ap[mi] = *(const bf16x8*)((char*)&Ps[wm + mi * 16 + c][0] + u8 * 8);
        }
#pragma unroll
        for (int vd = 0; vd < 4; vd++) {
          int pch = (half * 8 + kk2 * 4 + q) ^ cx;
          bv[vd] = *(const bf16x8*)&Vs[cur][vd * 16 + c][pch * 8];
        }
#pragma unroll
        for (int mi = 0; mi < 2; mi++)
#pragma unroll
          for (int vd = 0; vd < 4; vd++)
            O[mi][vd] = __builtin_amdgcn_mfma_f32_16x16x32_bf16(ap[mi], bv[vd], O[mi][vd], 0, 0, 0);
      }
    }
    // single barrier per tile: drains this iter's stage issues (vmcnt0) and
    // guarantees all waves finished reading buf[cur] before it is re-staged
    __syncthreads();
  }

  // epilogue: l = cross-lane rowsum; out = O / l / 3, scattered to original positions
  const float inv3 = 1.0f / 3.0f;
#pragma unroll
  for (int mi = 0; mi < 2; mi++)
#pragma unroll
    for (int rg = 0; rg < 4; rg++) {
      float l = lrow[mi][rg];
#pragma unroll
      for (int d = 1; d < 16; d <<= 1) l += __shfl_xor(l, d, 64);
      float invl = inv3 / l;
      int jj = jj0 + wm + mi * 16 + q * 4 + rg;
      int p = si * s + g + ((jj & 2047) << g);
      size_t base = ((size_t)(b * SEQ + p)) * EMB + h * HD;
#pragma unroll
      for (int vd = 0; vd < 4; vd++)
        xattn[base + vd * 16 + c] = (bf16_t)(O[mi][vd][rg] * invl);
    }
}

// ---------- LayerNorm (wave per row, 24B contiguous per lane) ----------
__global__ __launch_bounds__(256)
void k_ln(const bf16_t* __restrict__ x, const float* __restrict__ lnw,
          const float* __restrict__ lnb, bf16_t* __restrict__ y) {
  int wave = threadIdx.x >> 6, lane = threadIdx.x & 63;
  int row = blockIdx.x * 4 + wave;
  const bf16_t* xr = x + (size_t)row * EMB + lane * 12;
  bf16x4 v4[3];
#pragma unroll
  for (int j = 0; j < 3; j++) v4[j] = *(const bf16x4*)(xr + j * 4);
  float v[12], s = 0.f, s2 = 0.f;
#pragma unroll
  for (int j = 0; j < 12; j++) {
    v[j] = (float)v4[j >> 2][j & 3];
    s += v[j];
    s2 += v[j] * v[j];
  }
#pragma unroll
  for (int d = 1; d < 64; d <<= 1) { s += __shfl_xor(s, d, 64); s2 += __shfl_xor(s2, d, 64); }
  float mu = s * (1.f / 768.f);
  float var = s2 * (1.f / 768.f) - mu * mu;
  float rstd = rsqrtf(var + 1e-5f);
  const float4* wr = (const float4*)(lnw + lane * 12);
  const float4* br = (const float4*)(lnb + lane * 12);
  bf16_t* yr = y + (size_t)row * EMB + lane * 12;
#pragma unroll
  for (int j = 0; j < 3; j++) {
    float4 w = wr[j], bb = br[j];
    bf16x4 o;
    o[0] = (bf16_t)((v[j * 4 + 0] - mu) * rstd * w.x + bb.x);
    o[1] = (bf16_t)((v[j * 4 + 1] - mu) * rstd * w.y + bb.y);
    o[2] = (bf16_t)((v[j * 4 + 2] - mu) * rstd * w.z + bb.z);
    o[3] = (bf16_t)((v[j * 4 + 3] - mu) * rstd * w.w + bb.w);
    *(bf16x4*)(yr + j * 4) = o;
  }
}

extern "C" void kernel_launch(void* const* d_in, const int* in_sizes, int n_in,
                              void* d_out, int out_size, void* d_ws, size_t ws_size,
                              hipStream_t stream) {
  const float* query = (const float*)d_in[0];
  const float* key   = (const float*)d_in[1];
  const float* value = (const float*)d_in[2];
  const float* qkv_w = (const float*)d_in[3];
  const float* qkv_b = (const float*)d_in[4];
  const float* ln_w  = (const float*)d_in[5];
  const float* ln_b  = (const float*)d_in[6];
  const float* out_w = (const float*)d_in[7];
  const float* out_b = (const float*)d_in[8];
  float* out = (float*)d_out;

  char* ws = (char*)d_ws;
  const size_t A = (size_t)TOK * EMB * 2;   // 25,165,824 bytes per full-tensor slot
  bf16_t* xattn = (bf16_t*)(ws + 0 * A);
  bf16_t* xnorm = (bf16_t*)(ws + 1 * A);
  bf16_t* Vt    = (bf16_t*)(ws + 2 * A);    // V transposed/gathered, 14.7MB
  bf16_t* Vb    = (bf16_t*)(ws + 3 * A);    // V projected, [tok][768]
  bf16_t* Qg    = (bf16_t*)(ws + 4 * A);    // gathered Q (pre-scaled log2e/8), 14.7MB
  bf16_t* Kg    = (bf16_t*)(ws + 5 * A);    // gathered K, 14.7MB
  bf16_t* wqkv  = (bf16_t*)(ws + 6 * A);
  bf16_t* wout  = (bf16_t*)(ws + 6 * A + (size_t)2304 * 768 * 2);

  // 1. weight casts fp32 -> bf16 (inputs stay fp32; cast fused into qkv GEMM)
  k_cast<<<864, 256, 0, stream>>>(qkv_w, wqkv, 2304 * 768);
  k_cast<<<288, 256, 0, stream>>>(out_w, wout, 768 * 768);

  // 2. QKV projection from raw fp32 inputs (XCD-chunked swizzle) + fused gather
  k_gemm_qkv<<<2304, 256, 0, stream>>>(query, key, value, wqkv, qkv_b, Qg, Kg, Vb);

  // 3. V gather (transpose + slot-permute)
  dim3 gg(128, 12, 2);
  k_gather_v<<<gg, 256, 0, stream>>>(Vb, Vt);

  // 4. attention (zero xattn first: non-selected positions must be 0)
  hipMemsetAsync(xattn, 0, A, stream);
  k_attn<<<896, 256, 0, stream>>>(Qg, Kg, Vt, xattn);

  // 5. MAGNETO LN
  k_ln<<<4096, 256, 0, stream>>>(xattn, ln_w, ln_b, xnorm);

  // 6. output projection (XCD-chunked swizzle)
  k_gemm_out<<<768, 256, 0, stream>>>(xnorm, wout, out_b, out);
}

// Round 6
// 429.101 us; speedup vs baseline: 1.0110x; 1.0110x over previous
//
#include <hip/hip_runtime.h>
#include <hip/hip_bf16.h>
#include <math.h>

typedef __bf16 bf16_t;
typedef __bf16 bf16x8 __attribute__((ext_vector_type(8)));
typedef __bf16 bf16x4 __attribute__((ext_vector_type(4)));
typedef float f32x4 __attribute__((ext_vector_type(4)));

// ---------- async global->LDS (16B per lane), wave-uniform base + lane*16 ----------
__device__ __forceinline__ void async_ld16(const void* g, void* l) {
  __builtin_amdgcn_global_load_lds(
      (const __attribute__((address_space(1))) unsigned int*)g,
      (__attribute__((address_space(3))) unsigned int*)l, 16, 0, 0);
}

// ---------- problem constants ----------
#define BATCH 2
#define SEQ   8192
#define EMB   768
#define NHEAD 12
#define HD    64
#define TOK   (BATCH*SEQ)          // 16384
#define GATH_PER_B 57344           // sum over heads of L_h = 4*(8192+4096+2048)

// group of head h: g = h>>2 ; L = 8192>>g ; s = 2048<<g ; r = 1<<g ; off = g
__device__ __forceinline__ int headoff(int h) {
  int g = h >> 2;
  int base = (g == 0) ? 0 : ((g == 1) ? 32768 : 49152);
  return base + (h & 3) * (8192 >> g);
}

// exp2 via compiler intrinsic (scores pre-scaled by log2(e) upstream).
__device__ __forceinline__ float fast_exp2(float x) {
#if __has_builtin(__builtin_amdgcn_exp2f)
  return __builtin_amdgcn_exp2f(x);
#else
  return exp2f(x);
#endif
}

// ---------- fp32 -> bf16 cast (8 elems/thread, 16B stores) ----------
__global__ void k_cast(const float* __restrict__ in, bf16_t* __restrict__ out, int n) {
  int i = (blockIdx.x * blockDim.x + threadIdx.x) * 8;
  if (i < n) {
    float4 a = *(const float4*)(in + i);
    float4 b = *(const float4*)(in + i + 4);
    __attribute__((aligned(16))) bf16_t o[8] = {
        (bf16_t)a.x, (bf16_t)a.y, (bf16_t)a.z, (bf16_t)a.w,
        (bf16_t)b.x, (bf16_t)b.y, (bf16_t)b.z, (bf16_t)b.w};
    *(uint4*)(out + i) = *(uint4*)o;
  }
}

// ---------- QKV GEMM: fp32 A reg-staged (cast fused, LDS stays bf16), bf16 W DMA ----------
// A is the RAW fp32 input. Iter t: issue fp32 loads for tile t+1 into REGISTERS
// (64B/lane coalesced), compute tile t (hides L2 latency), then cvt->bf16 and
// ds_write_b128 into the next LDS buffer. LDS layout/size identical to the
// known-good bf16 path (32KB, same fragment reads, same conflict profile).
// 1-D grid of 2304 with XCD-chunked swizzle (8 XCDs x 288).
__global__ __launch_bounds__(256, 4)
void k_gemm_qkv(const float* __restrict__ qf, const float* __restrict__ kf,
                const float* __restrict__ vf, const bf16_t* __restrict__ wqkv,
                const float* __restrict__ qkv_bias,
                bf16_t* __restrict__ Qg, bf16_t* __restrict__ Kg, bf16_t* __restrict__ Vb) {
  const int N = 768, K = 768;
  int id = blockIdx.x;
  int wid = (id & 7) * 288 + (id >> 3);
  int z = wid / 768;
  int rem = wid - z * 768;
  int ytile = rem / 6;
  int xtile = rem - ytile * 6;
  int m0 = ytile * 128, n0 = xtile * 128;

  const float* A = (z == 0) ? qf : (z == 1) ? kf : vf;
  const bf16_t* W = wqkv + (size_t)z * N * K;
  const float* bias = qkv_bias + z * N;

  __shared__ bf16_t As[2][128][32];   // 16KB total (2 bufs) — same as round-4
  __shared__ bf16_t Bs[2][128][32];

  int tid = threadIdx.x;
  int wave = tid >> 6, lane = tid & 63;
  int q = lane >> 4, c = lane & 15;
  int wm = (wave & 1) * 64, wn = (wave >> 1) * 64;

  // per-thread A chunks: ch = tid*2+{0,1}; row=ch>>2, col8=(ch&3)*8 (8 bf16 = 16B)
  int chA = tid * 2;
  int rowA = chA >> 2, c8A = (chA & 3) << 3;   // second chunk: same row, c8A+8

  f32x4 rA[2][2];                     // staged fp32 for next tile (2 chunks x 8 f32)
  auto loadA = [&](int k0) {
    const float* src = A + (size_t)(m0 + rowA) * K + k0 + c8A;
    rA[0][0] = *(const f32x4*)src;
    rA[0][1] = *(const f32x4*)(src + 4);
    rA[1][0] = *(const f32x4*)(src + 8);
    rA[1][1] = *(const f32x4*)(src + 12);
  };
  auto writeA = [&](int bsel) {
#pragma unroll
    for (int u = 0; u < 2; ++u) {
      bf16x8 t;
#pragma unroll
      for (int j = 0; j < 4; j++) { t[j] = (bf16_t)rA[u][0][j]; t[4 + j] = (bf16_t)rA[u][1][j]; }
      *(bf16x8*)&As[bsel][rowA][c8A + u * 8] = t;
    }
  };
  auto stageW = [&](int k0, int bsel) {
#pragma unroll
    for (int it = 0; it < 2; ++it) {
      int ch = tid + it * 256;
      int row = ch >> 2, kb8 = (ch & 3) << 3;
      async_ld16(W + (size_t)(n0 + row) * K + k0 + kb8, &Bs[bsel][row][kb8]);
    }
  };

  f32x4 acc[4][4];
#pragma unroll
  for (int i = 0; i < 4; i++)
#pragma unroll
    for (int j = 0; j < 4; j++) acc[i][j] = (f32x4){0.f, 0.f, 0.f, 0.f};

  // prologue: tile 0 into buffer 0
  loadA(0);
  stageW(0, 0);
  writeA(0);
  __syncthreads();

#pragma unroll 2
  for (int kt = 0; kt < 24; ++kt) {
    int cur = kt & 1, nxt = cur ^ 1;
    // issue next tile's loads first: W direct-to-LDS, A to registers
    if (kt + 1 < 24) {
      stageW((kt + 1) * 32, nxt);
      loadA((kt + 1) * 32);
    }
    bf16x8 af[4], bfr[4];
#pragma unroll
    for (int mi = 0; mi < 4; mi++) af[mi] = *(const bf16x8*)&As[cur][wm + mi * 16 + c][q * 8];
#pragma unroll
    for (int nj = 0; nj < 4; nj++) bfr[nj] = *(const bf16x8*)&Bs[cur][wn + nj * 16 + c][q * 8];
#pragma unroll
    for (int mi = 0; mi < 4; mi++)
#pragma unroll
      for (int nj = 0; nj < 4; nj++)
        acc[mi][nj] = __builtin_amdgcn_mfma_f32_16x16x32_bf16(af[mi], bfr[nj], acc[mi][nj], 0, 0, 0);
    // A loads have had the whole MFMA block to return; convert + write next buffer
    if (kt + 1 < 24) writeA(nxt);
    // barrier: drains W DMA (vmcnt) + ds_writes; all waves done reading buf[cur]
    __syncthreads();
  }

  if (z == 2) {
#pragma unroll
    for (int mi = 0; mi < 4; mi++)
#pragma unroll
      for (int nj = 0; nj < 4; nj++)
#pragma unroll
        for (int rg = 0; rg < 4; rg++) {
          int row = m0 + wm + mi * 16 + q * 4 + rg;
          int col = n0 + wn + nj * 16 + c;
          Vb[(size_t)row * N + col] = (bf16_t)(acc[mi][nj][rg] + bias[col]);
        }
  } else {
    bf16_t* dst = (z == 0) ? Qg : Kg;
    // Q pre-scale folds 1/sqrt(64) AND log2(e) so attn can use raw 2^x
    float qscale = (z == 0) ? 0.125f * 1.44269504088896f : 1.0f;
#pragma unroll
    for (int mi = 0; mi < 4; mi++)
#pragma unroll
      for (int nj = 0; nj < 4; nj++) {
        int e = n0 + wn + nj * 16 + c;
        int h = e >> 6, dim = e & 63, g2 = h >> 2;
        int rm1 = (1 << g2) - 1, sh = 11 + g2;
        int smask = (2048 << g2) - 1;
        int ho = headoff(h);
#pragma unroll
        for (int rg = 0; rg < 4; rg++) {
          int row = m0 + wm + mi * 16 + q * 4 + rg;
          float v = (acc[mi][nj][rg] + bias[e]) * qscale;
          int bb = row >> 13, p = row & 8191;
          int t = (p & smask) - g2;           // off == g2
          if (t >= 0 && (t & rm1) == 0) {
            int jj = (p >> sh) * 2048 + (t >> g2);
            dst[(size_t)(bb * GATH_PER_B + ho + jj) * HD + dim] = (bf16_t)v;
          }
        }
      }
  }
}

// ---------- output GEMM: fp32 out (2-phase pipelined, XCD-chunked swizzle) ----------
__global__ __launch_bounds__(256, 4)
void k_gemm_out(const bf16_t* __restrict__ A, const bf16_t* __restrict__ W,
                const float* __restrict__ bias, float* __restrict__ C) {
  const int N = 768, K = 768;
  // 768 blocks = 8 XCDs x 96; work ordered (m-panel, n-tile)
  int id = blockIdx.x;
  int wid = (id & 7) * 96 + (id >> 3);
  int ytile = wid / 6;
  int xtile = wid - ytile * 6;
  int m0 = ytile * 128, n0 = xtile * 128;

  __shared__ bf16_t As[2][128][32];
  __shared__ bf16_t Bs[2][128][32];

  int tid = threadIdx.x;
  int wave = tid >> 6, lane = tid & 63;
  int q = lane >> 4, c = lane & 15;
  int wm = (wave & 1) * 64, wn = (wave >> 1) * 64;

  auto stage = [&](int k0, int bsel) {
#pragma unroll
    for (int it = 0; it < 2; ++it) {
      int ch = tid + it * 256;
      int row = ch >> 2, kb8 = (ch & 3) << 3;
      async_ld16(A + (size_t)(m0 + row) * K + k0 + kb8, &As[bsel][row][kb8]);
      async_ld16(W + (size_t)(n0 + row) * K + k0 + kb8, &Bs[bsel][row][kb8]);
    }
  };

  f32x4 acc[4][4];
#pragma unroll
  for (int i = 0; i < 4; i++)
#pragma unroll
    for (int j = 0; j < 4; j++) acc[i][j] = (f32x4){0.f, 0.f, 0.f, 0.f};

  stage(0, 0);
#pragma unroll 2
  for (int kt = 0; kt < 24; ++kt) {
    int cur = kt & 1;
    __syncthreads();
    if (kt + 1 < 24) stage((kt + 1) * 32, cur ^ 1);
    bf16x8 af[4], bfr[4];
#pragma unroll
    for (int mi = 0; mi < 4; mi++) af[mi] = *(const bf16x8*)&As[cur][wm + mi * 16 + c][q * 8];
#pragma unroll
    for (int nj = 0; nj < 4; nj++) bfr[nj] = *(const bf16x8*)&Bs[cur][wn + nj * 16 + c][q * 8];
#pragma unroll
    for (int mi = 0; mi < 4; mi++)
#pragma unroll
      for (int nj = 0; nj < 4; nj++)
        acc[mi][nj] = __builtin_amdgcn_mfma_f32_16x16x32_bf16(af[mi], bfr[nj], acc[mi][nj], 0, 0, 0);
  }
#pragma unroll
  for (int mi = 0; mi < 4; mi++)
#pragma unroll
    for (int nj = 0; nj < 4; nj++)
#pragma unroll
      for (int rg = 0; rg < 4; rg++) {
        int row = m0 + wm + mi * 16 + q * 4 + rg;
        int col = n0 + wn + nj * 16 + c;
        C[(size_t)row * N + col] = acc[mi][nj][rg] + bias[col];
      }
}

// ---------- V gather: Vb [tok][768] -> Vt [head][dim][L], slot-permuted ----------
__global__ __launch_bounds__(256)
void k_gather_v(const bf16_t* __restrict__ Vb, bf16_t* __restrict__ Vt) {
  int h = blockIdx.y, b = blockIdx.z;
  int g = h >> 2;
  int L = 8192 >> g;
  int jj0 = blockIdx.x * 64;
  if (jj0 >= L) return;
  int s = 2048 << g;
  int hb = b * GATH_PER_B + headoff(h);
  int tid = threadIdx.x;

  __shared__ bf16_t tile[64][72];

#pragma unroll
  for (int it = 0; it < 2; ++it) {
    int ch = tid + it * 256;            // 512 chunks: 64 rows x 8 chunks of 16B
    int rowl = ch >> 3, db = (ch & 7) << 3;
    int jj = jj0 + rowl;
    int p = (jj >> 11) * s + g + ((jj & 2047) << g);
    *(uint4*)&tile[rowl][db] = *(const uint4*)(Vb + ((size_t)(b * SEQ + p)) * EMB + h * HD + db);
  }
  __syncthreads();
  int dim = tid >> 2, sub = tid & 3;
  __attribute__((aligned(16))) bf16_t tmp[16];
#pragma unroll
  for (int sl = 0; sl < 16; sl++) {
    int t = sub * 16 + sl;
    int pos = (t & 3) * 16 + (t >> 2);
    tmp[sl] = tile[pos][dim];
  }
  size_t vdst = ((size_t)hb) * HD + (size_t)dim * L + jj0 + sub * 16;
  *(uint4*)(Vt + vdst) = *(uint4*)&tmp[0];
  *(uint4*)(Vt + vdst + 8) = *(uint4*)&tmp[8];
}

// ---------- flash attention ----------
// Double-buffered K/V staging (80KB LDS, 2 blocks/CU), single barrier per KV tile.
__global__ __launch_bounds__(256, 2)
void k_attn(const bf16_t* __restrict__ Qg, const bf16_t* __restrict__ Kg,
            const bf16_t* __restrict__ Vt, bf16_t* __restrict__ xattn) {
  // block id = qt*56 + seg: all 16 Q-tiles of a segment share an XCD (56 % 8 == 0)
  int u = blockIdx.x;
  int seg = u % 56, qt = u / 56;
  int b = seg / 28, t = seg % 28;
  int g, h, si;
  if (t < 16)      { g = 0; h = t >> 2;              si = t & 3; }
  else if (t < 24) { g = 1; h = 4 + ((t - 16) >> 1); si = (t - 16) & 1; }
  else             { g = 2; h = 8 + (t - 24);        si = 0; }
  int L = 8192 >> g, s = 2048 << g;
  int hb = b * GATH_PER_B + headoff(h);
  int jj0 = si * 2048 + qt * 128;
  int kvbase = si * 2048;

  __shared__ bf16_t Ps[128][64];        // 16KB: P half-tile round-trip; doubles as Q staging
  __shared__ bf16_t Ks[2][128][64];     // 32KB double-buffered
  __shared__ bf16_t Vs[2][64][128];     // 32KB double-buffered ([dim][slot], pre-permuted)

  int tid = threadIdx.x, wave = tid >> 6, lane = tid & 63;
  int q = lane >> 4, c = lane & 15;
  int cx = c & 7;
  int wm = wave * 32;

  auto stageK = [&](int kt, int bsel) {
#pragma unroll
    for (int it = 0; it < 4; ++it) {
      int ch = tid + it * 256;
      int row = ch >> 3, pc = ch & 7, lc = pc ^ (row & 7);
      async_ld16(Kg + ((size_t)(hb + kvbase + kt * 128 + row)) * HD + lc * 8,
                 &Ks[bsel][0][0] + ch * 8);
    }
  };
  auto stageV = [&](int kt, int bsel) {
#pragma unroll
    for (int it = 0; it < 4; ++it) {
      int ch = tid + it * 256;
      int dim = ch >> 4, pc = ch & 15, lc = pc ^ (dim & 7);
      async_ld16(Vt + ((size_t)hb) * HD + (size_t)dim * L + kvbase + kt * 128 + lc * 8,
                 &Vs[bsel][0][0] + ch * 8);
    }
  };

  // stage Q tile [128][64] into Ps area, chunk-swizzled, plus K0/V0 into buffer 0
  bf16_t* Qs = &Ps[0][0];
#pragma unroll
  for (int it = 0; it < 4; ++it) {
    int ch = tid + it * 256;
    int row = ch >> 3, pc = ch & 7, lc = pc ^ (row & 7);
    async_ld16(Qg + ((size_t)(hb + jj0 + row)) * HD + lc * 8, Qs + ch * 8);
  }
  stageK(0, 0);
  stageV(0, 0);
  __syncthreads();                      // Q + K0/V0 staged

  // Q fragments (wave-private Ps rows)
  bf16x8 aq[2][2];
#pragma unroll
  for (int mi = 0; mi < 2; mi++)
#pragma unroll
    for (int kq = 0; kq < 2; kq++) {
      int pch = (kq * 4 + q) ^ cx;
      aq[mi][kq] = *(const bf16x8*)(Qs + (size_t)(wm + mi * 16 + c) * HD + pch * 8);
    }

  float lrow[2][4];
  f32x4 O[2][4];
#pragma unroll
  for (int mi = 0; mi < 2; mi++)
#pragma unroll
    for (int rg = 0; rg < 4; rg++) lrow[mi][rg] = 0.f;
#pragma unroll
  for (int mi = 0; mi < 2; mi++)
#pragma unroll
    for (int vd = 0; vd < 4; vd++) O[mi][vd] = (f32x4){0.f, 0.f, 0.f, 0.f};

#pragma unroll 2
  for (int kt = 0; kt < 16; ++kt) {
    int cur = kt & 1;
    // issue next tile's staging before compute: latency hides under this tile's work
    if (kt < 15) {
      stageK(kt + 1, cur ^ 1);
      stageV(kt + 1, cur ^ 1);
    }

    // S = Q K^T  (Q pre-scaled by log2e/8; scores are in log2 domain)
    f32x4 Sv[2][8];
#pragma unroll
    for (int mi = 0; mi < 2; mi++)
#pragma unroll
      for (int nj = 0; nj < 8; nj++) Sv[mi][nj] = (f32x4){0.f, 0.f, 0.f, 0.f};
#pragma unroll
    for (int kq = 0; kq < 2; kq++) {
      int pch = (kq * 4 + q) ^ cx;
      bf16x8 bk[8];
#pragma unroll
      for (int nj = 0; nj < 8; nj++) bk[nj] = *(const bf16x8*)&Ks[cur][nj * 16 + c][pch * 8];
#pragma unroll
      for (int mi = 0; mi < 2; mi++)
#pragma unroll
        for (int nj = 0; nj < 8; nj++)
          Sv[mi][nj] = __builtin_amdgcn_mfma_f32_16x16x32_bf16(aq[mi][kq], bk[nj], Sv[mi][nj], 0, 0, 0);
    }

    // two KV halves of 64: exp2+pack 4 vals -> ds_write_b64 into Ps[128][64]; then PV
#pragma unroll
    for (int half = 0; half < 2; ++half) {
#pragma unroll
      for (int mi = 0; mi < 2; mi++)
#pragma unroll
        for (int rg = 0; rg < 4; rg++) {
          bf16x4 p4;
          float rs = 0.f;
#pragma unroll
          for (int j = 0; j < 4; j++) {
            float p = fast_exp2(Sv[mi][half * 4 + j][rg]);
            rs += p;
            p4[j] = (bf16_t)p;
          }
          lrow[mi][rg] += rs;
          int row = wm + mi * 16 + q * 4 + rg;
          int u8 = c ^ ((row & 7) << 1);          // 8B-unit swizzle
          *(bf16x4*)((char*)&Ps[row][0] + u8 * 8) = p4;
        }
      // no barrier: Ps rows wm..wm+31 wave-private (DS ops in-order within a wave)
#pragma unroll
      for (int kk2 = 0; kk2 < 2; ++kk2) {
        bf16x8 ap[2], bv[4];
#pragma unroll
        for (int mi = 0; mi < 2; mi++) {
          int u8 = (kk2 * 8 + q * 2) ^ (cx << 1); // even: b128-aligned
          ap[mi] = *(const bf16x8*)((char*)&Ps[wm + mi * 16 + c][0] + u8 * 8);
        }
#pragma unroll
        for (int vd = 0; vd < 4; vd++) {
          int pch = (half * 8 + kk2 * 4 + q) ^ cx;
          bv[vd] = *(const bf16x8*)&Vs[cur][vd * 16 + c][pch * 8];
        }
#pragma unroll
        for (int mi = 0; mi < 2; mi++)
#pragma unroll
          for (int vd = 0; vd < 4; vd++)
            O[mi][vd] = __builtin_amdgcn_mfma_f32_16x16x32_bf16(ap[mi], bv[vd], O[mi][vd], 0, 0, 0);
      }
    }
    // single barrier per tile: drains this iter's stage issues (vmcnt0) and
    // guarantees all waves finished reading buf[cur] before it is re-staged
    __syncthreads();
  }

  // epilogue: l = cross-lane rowsum; out = O / l / 3, scattered to original positions
  const float inv3 = 1.0f / 3.0f;
#pragma unroll
  for (int mi = 0; mi < 2; mi++)
#pragma unroll
    for (int rg = 0; rg < 4; rg++) {
      float l = lrow[mi][rg];
#pragma unroll
      for (int d = 1; d < 16; d <<= 1) l += __shfl_xor(l, d, 64);
      float invl = inv3 / l;
      int jj = jj0 + wm + mi * 16 + q * 4 + rg;
      int p = si * s + g + ((jj & 2047) << g);
      size_t base = ((size_t)(b * SEQ + p)) * EMB + h * HD;
#pragma unroll
      for (int vd = 0; vd < 4; vd++)
        xattn[base + vd * 16 + c] = (bf16_t)(O[mi][vd][rg] * invl);
    }
}

// ---------- LayerNorm (wave per row, 24B contiguous per lane) ----------
__global__ __launch_bounds__(256)
void k_ln(const bf16_t* __restrict__ x, const float* __restrict__ lnw,
          const float* __restrict__ lnb, bf16_t* __restrict__ y) {
  int wave = threadIdx.x >> 6, lane = threadIdx.x & 63;
  int row = blockIdx.x * 4 + wave;
  const bf16_t* xr = x + (size_t)row * EMB + lane * 12;
  bf16x4 v4[3];
#pragma unroll
  for (int j = 0; j < 3; j++) v4[j] = *(const bf16x4*)(xr + j * 4);
  float v[12], s = 0.f, s2 = 0.f;
#pragma unroll
  for (int j = 0; j < 12; j++) {
    v[j] = (float)v4[j >> 2][j & 3];
    s += v[j];
    s2 += v[j] * v[j];
  }
#pragma unroll
  for (int d = 1; d < 64; d <<= 1) { s += __shfl_xor(s, d, 64); s2 += __shfl_xor(s2, d, 64); }
  float mu = s * (1.f / 768.f);
  float var = s2 * (1.f / 768.f) - mu * mu;
  float rstd = rsqrtf(var + 1e-5f);
  const float4* wr = (const float4*)(lnw + lane * 12);
  const float4* br = (const float4*)(lnb + lane * 12);
  bf16_t* yr = y + (size_t)row * EMB + lane * 12;
#pragma unroll
  for (int j = 0; j < 3; j++) {
    float4 w = wr[j], bb = br[j];
    bf16x4 o;
    o[0] = (bf16_t)((v[j * 4 + 0] - mu) * rstd * w.x + bb.x);
    o[1] = (bf16_t)((v[j * 4 + 1] - mu) * rstd * w.y + bb.y);
    o[2] = (bf16_t)((v[j * 4 + 2] - mu) * rstd * w.z + bb.z);
    o[3] = (bf16_t)((v[j * 4 + 3] - mu) * rstd * w.w + bb.w);
    *(bf16x4*)(yr + j * 4) = o;
  }
}

extern "C" void kernel_launch(void* const* d_in, const int* in_sizes, int n_in,
                              void* d_out, int out_size, void* d_ws, size_t ws_size,
                              hipStream_t stream) {
  const float* query = (const float*)d_in[0];
  const float* key   = (const float*)d_in[1];
  const float* value = (const float*)d_in[2];
  const float* qkv_w = (const float*)d_in[3];
  const float* qkv_b = (const float*)d_in[4];
  const float* ln_w  = (const float*)d_in[5];
  const float* ln_b  = (const float*)d_in[6];
  const float* out_w = (const float*)d_in[7];
  const float* out_b = (const float*)d_in[8];
  float* out = (float*)d_out;

  char* ws = (char*)d_ws;
  const size_t A = (size_t)TOK * EMB * 2;   // 25,165,824 bytes per full-tensor slot
  bf16_t* xattn = (bf16_t*)(ws + 0 * A);
  bf16_t* xnorm = (bf16_t*)(ws + 1 * A);
  bf16_t* Vt    = (bf16_t*)(ws + 2 * A);    // V transposed/gathered, 14.7MB
  bf16_t* Vb    = (bf16_t*)(ws + 3 * A);    // V projected, [tok][768]
  bf16_t* Qg    = (bf16_t*)(ws + 4 * A);    // gathered Q (pre-scaled log2e/8), 14.7MB
  bf16_t* Kg    = (bf16_t*)(ws + 5 * A);    // gathered K, 14.7MB
  bf16_t* wqkv  = (bf16_t*)(ws + 6 * A);
  bf16_t* wout  = (bf16_t*)(ws + 6 * A + (size_t)2304 * 768 * 2);

  // 1. weight casts fp32 -> bf16 (inputs stay fp32; input cast fused into qkv GEMM)
  k_cast<<<864, 256, 0, stream>>>(qkv_w, wqkv, 2304 * 768);
  k_cast<<<288, 256, 0, stream>>>(out_w, wout, 768 * 768);

  // 2. QKV projection from raw fp32 inputs (reg-staged cast, XCD-chunked swizzle)
  k_gemm_qkv<<<2304, 256, 0, stream>>>(query, key, value, wqkv, qkv_b, Qg, Kg, Vb);

  // 3. V gather (transpose + slot-permute)
  dim3 gg(128, 12, 2);
  k_gather_v<<<gg, 256, 0, stream>>>(Vb, Vt);

  // 4. attention (zero xattn first: non-selected positions must be 0)
  hipMemsetAsync(xattn, 0, A, stream);
  k_attn<<<896, 256, 0, stream>>>(Qg, Kg, Vt, xattn);

  // 5. MAGNETO LN
  k_ln<<<4096, 256, 0, stream>>>(xattn, ln_w, ln_b, xnorm);

  // 6. output projection (XCD-chunked swizzle)
  k_gemm_out<<<768, 256, 0, stream>>>(xnorm, wout, out_b, out);
}

// Round 8
// 412.815 us; speedup vs baseline: 1.0508x; 1.0395x over previous
//
#include <hip/hip_runtime.h>
#include <hip/hip_bf16.h>
#include <math.h>

typedef __bf16 bf16_t;
typedef __bf16 bf16x8 __attribute__((ext_vector_type(8)));
typedef __bf16 bf16x4 __attribute__((ext_vector_type(4)));
typedef float f32x4 __attribute__((ext_vector_type(4)));

// ---------- async global->LDS (16B per lane), wave-uniform base + lane*16 ----------
__device__ __forceinline__ void async_ld16(const void* g, void* l) {
  __builtin_amdgcn_global_load_lds(
      (const __attribute__((address_space(1))) unsigned int*)g,
      (__attribute__((address_space(3))) unsigned int*)l, 16, 0, 0);
}

// ---------- problem constants ----------
#define BATCH 2
#define SEQ   8192
#define EMB   768
#define NHEAD 12
#define HD    64
#define TOK   (BATCH*SEQ)          // 16384
#define GATH_PER_B 57344           // sum over heads of L_h = 4*(8192+4096+2048)

// group of head h: g = h>>2 ; L = 8192>>g ; s = 2048<<g ; r = 1<<g ; off = g
__device__ __forceinline__ int headoff(int h) {
  int g = h >> 2;
  int base = (g == 0) ? 0 : ((g == 1) ? 32768 : 49152);
  return base + (h & 3) * (8192 >> g);
}

// exp2 via compiler intrinsic (scores pre-scaled by log2(e) upstream).
__device__ __forceinline__ float fast_exp2(float x) {
#if __has_builtin(__builtin_amdgcn_exp2f)
  return __builtin_amdgcn_exp2f(x);
#else
  return exp2f(x);
#endif
}

// ---------- merged fp32 -> bf16 casts: 5 regions in ONE launch ----------
// regions (blocks): [0,6144) query, [6144,12288) key, [12288,18432) value,
// [18432,19296) qkv_w (864), [19296,19584) out_w (288). All exact multiples
// of 256*8 elements, so no bounds checks.
__global__ __launch_bounds__(256)
void k_cast_all(const float* __restrict__ q, const float* __restrict__ k,
                const float* __restrict__ v, const float* __restrict__ qkvw,
                const float* __restrict__ outw,
                bf16_t* __restrict__ qb, bf16_t* __restrict__ kb,
                bf16_t* __restrict__ vb, bf16_t* __restrict__ wqkv,
                bf16_t* __restrict__ wout) {
  int bid = blockIdx.x;
  const float* src;
  bf16_t* dst;
  int base;
  if (bid < 6144)       { src = q;    dst = qb;   base = bid; }
  else if (bid < 12288) { src = k;    dst = kb;   base = bid - 6144; }
  else if (bid < 18432) { src = v;    dst = vb;   base = bid - 12288; }
  else if (bid < 19296) { src = qkvw; dst = wqkv; base = bid - 18432; }
  else                  { src = outw; dst = wout; base = bid - 19296; }
  int i = (base * 256 + threadIdx.x) * 8;
  float4 a = *(const float4*)(src + i);
  float4 b = *(const float4*)(src + i + 4);
  __attribute__((aligned(16))) bf16_t o[8] = {
      (bf16_t)a.x, (bf16_t)a.y, (bf16_t)a.z, (bf16_t)a.w,
      (bf16_t)b.x, (bf16_t)b.y, (bf16_t)b.z, (bf16_t)b.w};
  *(uint4*)(dst + i) = *(uint4*)o;
}

// ---------- QKV GEMM (bf16 A via async DMA, 2-phase pipelined) + fused gather ----------
// 1-D grid of 2304 with XCD-chunked swizzle: work ordered (z, m-panel, n-tile) so the
// 6 blocks sharing one 128x768 A-panel run consecutively ON THE SAME XCD's L2.
__global__ __launch_bounds__(256, 2)
void k_gemm_qkv(const bf16_t* __restrict__ qb, const bf16_t* __restrict__ kb,
                const bf16_t* __restrict__ vb, const bf16_t* __restrict__ wqkv,
                const float* __restrict__ qkv_bias,
                bf16_t* __restrict__ Qg, bf16_t* __restrict__ Kg, bf16_t* __restrict__ Vb) {
  const int N = 768, K = 768;
  // XCD-chunked bijective swizzle: 2304 blocks = 8 XCDs x 288
  int id = blockIdx.x;
  int wid = (id & 7) * 288 + (id >> 3);
  int z = wid / 768;
  int rem = wid - z * 768;
  int ytile = rem / 6;
  int xtile = rem - ytile * 6;
  int m0 = ytile * 128, n0 = xtile * 128;

  const bf16_t* A = (z == 0) ? qb : (z == 1) ? kb : vb;
  const bf16_t* W = wqkv + (size_t)z * N * K;
  const float* bias = qkv_bias + z * N;

  __shared__ bf16_t As[2][128][32];
  __shared__ bf16_t Bs[2][128][32];

  int tid = threadIdx.x;
  int wave = tid >> 6, lane = tid & 63;
  int q = lane >> 4, c = lane & 15;
  int wm = (wave & 1) * 64, wn = (wave >> 1) * 64;

  auto stage = [&](int k0, int bsel) {
#pragma unroll
    for (int it = 0; it < 2; ++it) {
      int ch = tid + it * 256;          // 512 chunks of 16B
      int row = ch >> 2, kb8 = (ch & 3) << 3;
      async_ld16(A + (size_t)(m0 + row) * K + k0 + kb8, &As[bsel][row][kb8]);
      async_ld16(W + (size_t)(n0 + row) * K + k0 + kb8, &Bs[bsel][row][kb8]);
    }
  };

  f32x4 acc[4][4];
#pragma unroll
  for (int i = 0; i < 4; i++)
#pragma unroll
    for (int j = 0; j < 4; j++) acc[i][j] = (f32x4){0.f, 0.f, 0.f, 0.f};

  stage(0, 0);
#pragma unroll 2
  for (int kt = 0; kt < 24; ++kt) {
    int cur = kt & 1;
    __syncthreads();                    // buf[cur] staged; prior reads of buf[cur^1] done
    if (kt + 1 < 24) stage((kt + 1) * 32, cur ^ 1);
    bf16x8 af[4], bfr[4];
#pragma unroll
    for (int mi = 0; mi < 4; mi++) af[mi] = *(const bf16x8*)&As[cur][wm + mi * 16 + c][q * 8];
#pragma unroll
    for (int nj = 0; nj < 4; nj++) bfr[nj] = *(const bf16x8*)&Bs[cur][wn + nj * 16 + c][q * 8];
#pragma unroll
    for (int mi = 0; mi < 4; mi++)
#pragma unroll
      for (int nj = 0; nj < 4; nj++)
        acc[mi][nj] = __builtin_amdgcn_mfma_f32_16x16x32_bf16(af[mi], bfr[nj], acc[mi][nj], 0, 0, 0);
  }

  if (z == 2) {
#pragma unroll
    for (int mi = 0; mi < 4; mi++)
#pragma unroll
      for (int nj = 0; nj < 4; nj++)
#pragma unroll
        for (int rg = 0; rg < 4; rg++) {
          int row = m0 + wm + mi * 16 + q * 4 + rg;
          int col = n0 + wn + nj * 16 + c;
          Vb[(size_t)row * N + col] = (bf16_t)(acc[mi][nj][rg] + bias[col]);
        }
  } else {
    bf16_t* dst = (z == 0) ? Qg : Kg;
    // Q pre-scale folds 1/sqrt(64) AND log2(e) so attn can use raw 2^x
    float qscale = (z == 0) ? 0.125f * 1.44269504088896f : 1.0f;
#pragma unroll
    for (int mi = 0; mi < 4; mi++)
#pragma unroll
      for (int nj = 0; nj < 4; nj++) {
        int e = n0 + wn + nj * 16 + c;
        int h = e >> 6, dim = e & 63, g2 = h >> 2;
        int rm1 = (1 << g2) - 1, sh = 11 + g2;
        int smask = (2048 << g2) - 1;
        int ho = headoff(h);
#pragma unroll
        for (int rg = 0; rg < 4; rg++) {
          int row = m0 + wm + mi * 16 + q * 4 + rg;
          float v = (acc[mi][nj][rg] + bias[e]) * qscale;
          int bb = row >> 13, p = row & 8191;
          int t = (p & smask) - g2;           // off == g2
          if (t >= 0 && (t & rm1) == 0) {
            int jj = (p >> sh) * 2048 + (t >> g2);
            dst[(size_t)(bb * GATH_PER_B + ho + jj) * HD + dim] = (bf16_t)v;
          }
        }
      }
  }
}

// ---------- output GEMM: fp32 out (2-phase pipelined, XCD-chunked swizzle) ----------
__global__ __launch_bounds__(256, 2)
void k_gemm_out(const bf16_t* __restrict__ A, const bf16_t* __restrict__ W,
                const float* __restrict__ bias, float* __restrict__ C) {
  const int N = 768, K = 768;
  // 768 blocks = 8 XCDs x 96; work ordered (m-panel, n-tile)
  int id = blockIdx.x;
  int wid = (id & 7) * 96 + (id >> 3);
  int ytile = wid / 6;
  int xtile = wid - ytile * 6;
  int m0 = ytile * 128, n0 = xtile * 128;

  __shared__ bf16_t As[2][128][32];
  __shared__ bf16_t Bs[2][128][32];

  int tid = threadIdx.x;
  int wave = tid >> 6, lane = tid & 63;
  int q = lane >> 4, c = lane & 15;
  int wm = (wave & 1) * 64, wn = (wave >> 1) * 64;

  auto stage = [&](int k0, int bsel) {
#pragma unroll
    for (int it = 0; it < 2; ++it) {
      int ch = tid + it * 256;
      int row = ch >> 2, kb8 = (ch & 3) << 3;
      async_ld16(A + (size_t)(m0 + row) * K + k0 + kb8, &As[bsel][row][kb8]);
      async_ld16(W + (size_t)(n0 + row) * K + k0 + kb8, &Bs[bsel][row][kb8]);
    }
  };

  f32x4 acc[4][4];
#pragma unroll
  for (int i = 0; i < 4; i++)
#pragma unroll
    for (int j = 0; j < 4; j++) acc[i][j] = (f32x4){0.f, 0.f, 0.f, 0.f};

  stage(0, 0);
#pragma unroll 2
  for (int kt = 0; kt < 24; ++kt) {
    int cur = kt & 1;
    __syncthreads();
    if (kt + 1 < 24) stage((kt + 1) * 32, cur ^ 1);
    bf16x8 af[4], bfr[4];
#pragma unroll
    for (int mi = 0; mi < 4; mi++) af[mi] = *(const bf16x8*)&As[cur][wm + mi * 16 + c][q * 8];
#pragma unroll
    for (int nj = 0; nj < 4; nj++) bfr[nj] = *(const bf16x8*)&Bs[cur][wn + nj * 16 + c][q * 8];
#pragma unroll
    for (int mi = 0; mi < 4; mi++)
#pragma unroll
      for (int nj = 0; nj < 4; nj++)
        acc[mi][nj] = __builtin_amdgcn_mfma_f32_16x16x32_bf16(af[mi], bfr[nj], acc[mi][nj], 0, 0, 0);
  }
#pragma unroll
  for (int mi = 0; mi < 4; mi++)
#pragma unroll
    for (int nj = 0; nj < 4; nj++)
#pragma unroll
      for (int rg = 0; rg < 4; rg++) {
        int row = m0 + wm + mi * 16 + q * 4 + rg;
        int col = n0 + wn + nj * 16 + c;
        C[(size_t)row * N + col] = acc[mi][nj][rg] + bias[col];
      }
}

// ---------- V gather: Vb [tok][768] -> Vt [head][dim][L], slot-permuted ----------
// compact grid: 896 useful (h, jj0) pairs per batch (no early-return blocks)
__global__ __launch_bounds__(256)
void k_gather_v(const bf16_t* __restrict__ Vb, bf16_t* __restrict__ Vt) {
  int u = blockIdx.x, b = blockIdx.y;
  int h, jj0;
  if (u < 512)      { h = u >> 7;              jj0 = (u & 127) * 64; }
  else if (u < 768) { int w = u - 512; h = 4 + (w >> 6); jj0 = (w & 63) * 64; }
  else              { int w = u - 768; h = 8 + (w >> 5); jj0 = (w & 31) * 64; }
  int g = h >> 2;
  int L = 8192 >> g;
  int s = 2048 << g;
  int hb = b * GATH_PER_B + headoff(h);
  int tid = threadIdx.x;

  __shared__ bf16_t tile[64][72];

#pragma unroll
  for (int it = 0; it < 2; ++it) {
    int ch = tid + it * 256;            // 512 chunks: 64 rows x 8 chunks of 16B
    int rowl = ch >> 3, db = (ch & 7) << 3;
    int jj = jj0 + rowl;
    int p = (jj >> 11) * s + g + ((jj & 2047) << g);
    *(uint4*)&tile[rowl][db] = *(const uint4*)(Vb + ((size_t)(b * SEQ + p)) * EMB + h * HD + db);
  }
  __syncthreads();
  int dim = tid >> 2, sub = tid & 3;
  __attribute__((aligned(16))) bf16_t tmp[16];
#pragma unroll
  for (int sl = 0; sl < 16; sl++) {
    int t = sub * 16 + sl;
    int pos = (t & 3) * 16 + (t >> 2);
    tmp[sl] = tile[pos][dim];
  }
  size_t vdst = ((size_t)hb) * HD + (size_t)dim * L + jj0 + sub * 16;
  *(uint4*)(Vt + vdst) = *(uint4*)&tmp[0];
  *(uint4*)(Vt + vdst + 8) = *(uint4*)&tmp[8];
}

// ---------- flash attention ----------
// Double-buffered K/V staging (80KB LDS, 2 blocks/CU), single barrier per KV tile.
__global__ __launch_bounds__(256, 2)
void k_attn(const bf16_t* __restrict__ Qg, const bf16_t* __restrict__ Kg,
            const bf16_t* __restrict__ Vt, bf16_t* __restrict__ xattn) {
  // block id = qt*56 + seg: all 16 Q-tiles of a segment share an XCD (56 % 8 == 0)
  int u = blockIdx.x;
  int seg = u % 56, qt = u / 56;
  int b = seg / 28, t = seg % 28;
  int g, h, si;
  if (t < 16)      { g = 0; h = t >> 2;              si = t & 3; }
  else if (t < 24) { g = 1; h = 4 + ((t - 16) >> 1); si = (t - 16) & 1; }
  else             { g = 2; h = 8 + (t - 24);        si = 0; }
  int L = 8192 >> g, s = 2048 << g;
  int hb = b * GATH_PER_B + headoff(h);
  int jj0 = si * 2048 + qt * 128;
  int kvbase = si * 2048;

  __shared__ bf16_t Ps[128][64];        // 16KB: P half-tile round-trip; doubles as Q staging
  __shared__ bf16_t Ks[2][128][64];     // 32KB double-buffered
  __shared__ bf16_t Vs[2][64][128];     // 32KB double-buffered ([dim][slot], pre-permuted)

  int tid = threadIdx.x, wave = tid >> 6, lane = tid & 63;
  int q = lane >> 4, c = lane & 15;
  int cx = c & 7;
  int wm = wave * 32;

  auto stageK = [&](int kt, int bsel) {
#pragma unroll
    for (int it = 0; it < 4; ++it) {
      int ch = tid + it * 256;
      int row = ch >> 3, pc = ch & 7, lc = pc ^ (row & 7);
      async_ld16(Kg + ((size_t)(hb + kvbase + kt * 128 + row)) * HD + lc * 8,
                 &Ks[bsel][0][0] + ch * 8);
    }
  };
  auto stageV = [&](int kt, int bsel) {
#pragma unroll
    for (int it = 0; it < 4; ++it) {
      int ch = tid + it * 256;
      int dim = ch >> 4, pc = ch & 15, lc = pc ^ (dim & 7);
      async_ld16(Vt + ((size_t)hb) * HD + (size_t)dim * L + kvbase + kt * 128 + lc * 8,
                 &Vs[bsel][0][0] + ch * 8);
    }
  };

  // stage Q tile [128][64] into Ps area, chunk-swizzled, plus K0/V0 into buffer 0
  bf16_t* Qs = &Ps[0][0];
#pragma unroll
  for (int it = 0; it < 4; ++it) {
    int ch = tid + it * 256;
    int row = ch >> 3, pc = ch & 7, lc = pc ^ (row & 7);
    async_ld16(Qg + ((size_t)(hb + jj0 + row)) * HD + lc * 8, Qs + ch * 8);
  }
  stageK(0, 0);
  stageV(0, 0);
  __syncthreads();                      // Q + K0/V0 staged

  // Q fragments (wave-private Ps rows)
  bf16x8 aq[2][2];
#pragma unroll
  for (int mi = 0; mi < 2; mi++)
#pragma unroll
    for (int kq = 0; kq < 2; kq++) {
      int pch = (kq * 4 + q) ^ cx;
      aq[mi][kq] = *(const bf16x8*)(Qs + (size_t)(wm + mi * 16 + c) * HD + pch * 8);
    }

  float lrow[2][4];
  f32x4 O[2][4];
#pragma unroll
  for (int mi = 0; mi < 2; mi++)
#pragma unroll
    for (int rg = 0; rg < 4; rg++) lrow[mi][rg] = 0.f;
#pragma unroll
  for (int mi = 0; mi < 2; mi++)
#pragma unroll
    for (int vd = 0; vd < 4; vd++) O[mi][vd] = (f32x4){0.f, 0.f, 0.f, 0.f};

#pragma unroll 2
  for (int kt = 0; kt < 16; ++kt) {
    int cur = kt & 1;
    // issue next tile's staging before compute: latency hides under this tile's work
    if (kt < 15) {
      stageK(kt + 1, cur ^ 1);
      stageV(kt + 1, cur ^ 1);
    }

    // S = Q K^T  (Q pre-scaled by log2e/8; scores are in log2 domain)
    f32x4 Sv[2][8];
#pragma unroll
    for (int mi = 0; mi < 2; mi++)
#pragma unroll
      for (int nj = 0; nj < 8; nj++) Sv[mi][nj] = (f32x4){0.f, 0.f, 0.f, 0.f};
#pragma unroll
    for (int kq = 0; kq < 2; kq++) {
      int pch = (kq * 4 + q) ^ cx;
      bf16x8 bk[8];
#pragma unroll
      for (int nj = 0; nj < 8; nj++) bk[nj] = *(const bf16x8*)&Ks[cur][nj * 16 + c][pch * 8];
#pragma unroll
      for (int mi = 0; mi < 2; mi++)
#pragma unroll
        for (int nj = 0; nj < 8; nj++)
          Sv[mi][nj] = __builtin_amdgcn_mfma_f32_16x16x32_bf16(aq[mi][kq], bk[nj], Sv[mi][nj], 0, 0, 0);
    }

    // two KV halves of 64: exp2+pack 4 vals -> ds_write_b64 into Ps[128][64]; then PV
#pragma unroll
    for (int half = 0; half < 2; ++half) {
#pragma unroll
      for (int mi = 0; mi < 2; mi++)
#pragma unroll
        for (int rg = 0; rg < 4; rg++) {
          bf16x4 p4;
          float rs = 0.f;
#pragma unroll
          for (int j = 0; j < 4; j++) {
            float p = fast_exp2(Sv[mi][half * 4 + j][rg]);
            rs += p;
            p4[j] = (bf16_t)p;
          }
          lrow[mi][rg] += rs;
          int row = wm + mi * 16 + q * 4 + rg;
          int u8 = c ^ ((row & 7) << 1);          // 8B-unit swizzle
          *(bf16x4*)((char*)&Ps[row][0] + u8 * 8) = p4;
        }
      // no barrier: Ps rows wm..wm+31 wave-private (DS ops in-order within a wave)
#pragma unroll
      for (int kk2 = 0; kk2 < 2; ++kk2) {
        bf16x8 ap[2], bv[4];
#pragma unroll
        for (int mi = 0; mi < 2; mi++) {
          int u8 = (kk2 * 8 + q * 2) ^ (cx << 1); // even: b128-aligned
          ap[mi] = *(const bf16x8*)((char*)&Ps[wm + mi * 16 + c][0] + u8 * 8);
        }
#pragma unroll
        for (int vd = 0; vd < 4; vd++) {
          int pch = (half * 8 + kk2 * 4 + q) ^ cx;
          bv[vd] = *(const bf16x8*)&Vs[cur][vd * 16 + c][pch * 8];
        }
#pragma unroll
        for (int mi = 0; mi < 2; mi++)
#pragma unroll
          for (int vd = 0; vd < 4; vd++)
            O[mi][vd] = __builtin_amdgcn_mfma_f32_16x16x32_bf16(ap[mi], bv[vd], O[mi][vd], 0, 0, 0);
      }
    }
    // single barrier per tile: drains this iter's stage issues (vmcnt0) and
    // guarantees all waves finished reading buf[cur] before it is re-staged
    __syncthreads();
  }

  // epilogue: l = cross-lane rowsum; out = O / l / 3, scattered to original positions
  const float inv3 = 1.0f / 3.0f;
#pragma unroll
  for (int mi = 0; mi < 2; mi++)
#pragma unroll
    for (int rg = 0; rg < 4; rg++) {
      float l = lrow[mi][rg];
#pragma unroll
      for (int d = 1; d < 16; d <<= 1) l += __shfl_xor(l, d, 64);
      float invl = inv3 / l;
      int jj = jj0 + wm + mi * 16 + q * 4 + rg;
      int p = si * s + g + ((jj & 2047) << g);
      size_t base = ((size_t)(b * SEQ + p)) * EMB + h * HD;
#pragma unroll
      for (int vd = 0; vd < 4; vd++)
        xattn[base + vd * 16 + c] = (bf16_t)(O[mi][vd][rg] * invl);
    }
}

// ---------- LayerNorm (wave per row, 24B contiguous per lane) ----------
__global__ __launch_bounds__(256)
void k_ln(const bf16_t* __restrict__ x, const float* __restrict__ lnw,
          const float* __restrict__ lnb, bf16_t* __restrict__ y) {
  int wave = threadIdx.x >> 6, lane = threadIdx.x & 63;
  int row = blockIdx.x * 4 + wave;
  const bf16_t* xr = x + (size_t)row * EMB + lane * 12;
  bf16x4 v4[3];
#pragma unroll
  for (int j = 0; j < 3; j++) v4[j] = *(const bf16x4*)(xr + j * 4);
  float v[12], s = 0.f, s2 = 0.f;
#pragma unroll
  for (int j = 0; j < 12; j++) {
    v[j] = (float)v4[j >> 2][j & 3];
    s += v[j];
    s2 += v[j] * v[j];
  }
#pragma unroll
  for (int d = 1; d < 64; d <<= 1) { s += __shfl_xor(s, d, 64); s2 += __shfl_xor(s2, d, 64); }
  float mu = s * (1.f / 768.f);
  float var = s2 * (1.f / 768.f) - mu * mu;
  float rstd = rsqrtf(var + 1e-5f);
  const float4* wr = (const float4*)(lnw + lane * 12);
  const float4* br = (const float4*)(lnb + lane * 12);
  bf16_t* yr = y + (size_t)row * EMB + lane * 12;
#pragma unroll
  for (int j = 0; j < 3; j++) {
    float4 w = wr[j], bb = br[j];
    bf16x4 o;
    o[0] = (bf16_t)((v[j * 4 + 0] - mu) * rstd * w.x + bb.x);
    o[1] = (bf16_t)((v[j * 4 + 1] - mu) * rstd * w.y + bb.y);
    o[2] = (bf16_t)((v[j * 4 + 2] - mu) * rstd * w.z + bb.z);
    o[3] = (bf16_t)((v[j * 4 + 3] - mu) * rstd * w.w + bb.w);
    *(bf16x4*)(yr + j * 4) = o;
  }
}

extern "C" void kernel_launch(void* const* d_in, const int* in_sizes, int n_in,
                              void* d_out, int out_size, void* d_ws, size_t ws_size,
                              hipStream_t stream) {
  const float* query = (const float*)d_in[0];
  const float* key   = (const float*)d_in[1];
  const float* value = (const float*)d_in[2];
  const float* qkv_w = (const float*)d_in[3];
  const float* qkv_b = (const float*)d_in[4];
  const float* ln_w  = (const float*)d_in[5];
  const float* ln_b  = (const float*)d_in[6];
  const float* out_w = (const float*)d_in[7];
  const float* out_b = (const float*)d_in[8];
  float* out = (float*)d_out;

  char* ws = (char*)d_ws;
  const size_t A = (size_t)TOK * EMB * 2;   // 25,165,824 bytes per full-tensor slot
  bf16_t* qb    = (bf16_t*)(ws + 0 * A);    // bf16 query  (later: xattn)
  bf16_t* kb    = (bf16_t*)(ws + 1 * A);    // bf16 key    (later: xnorm)
  bf16_t* vb    = (bf16_t*)(ws + 2 * A);    // bf16 value  (later: Vt, 14.7MB)
  bf16_t* Vb    = (bf16_t*)(ws + 3 * A);    // V projected, [tok][768]
  bf16_t* Qg    = (bf16_t*)(ws + 4 * A);    // gathered Q (pre-scaled log2e/8), 14.7MB
  bf16_t* Kg    = (bf16_t*)(ws + 5 * A);    // gathered K, 14.7MB
  bf16_t* wqkv  = (bf16_t*)(ws + 6 * A);
  bf16_t* wout  = (bf16_t*)(ws + 6 * A + (size_t)2304 * 768 * 2);
  // aliases (stream-ordered, lifetimes disjoint):
  bf16_t* Vt    = vb;   // vb dead after qkv GEMM
  bf16_t* xattn = qb;   // qb dead after qkv GEMM
  bf16_t* xnorm = kb;   // kb dead after qkv GEMM

  // 1. ALL fp32 -> bf16 casts in one launch (3 inputs + 2 weights)
  k_cast_all<<<19584, 256, 0, stream>>>(query, key, value, qkv_w, out_w,
                                        qb, kb, vb, wqkv, wout);

  // 2. QKV projection (XCD-chunked swizzle) + fused Q/K dilated-gather epilogue
  k_gemm_qkv<<<2304, 256, 0, stream>>>(qb, kb, vb, wqkv, qkv_b, Qg, Kg, Vb);

  // 3. V gather (transpose + slot-permute), compact grid: 896 useful blocks x 2 batches
  dim3 gg(896, 2);
  k_gather_v<<<gg, 256, 0, stream>>>(Vb, Vt);

  // 4. attention (zero xattn first: non-selected positions must be 0)
  hipMemsetAsync(xattn, 0, A, stream);
  k_attn<<<896, 256, 0, stream>>>(Qg, Kg, Vt, xattn);

  // 5. MAGNETO LN
  k_ln<<<4096, 256, 0, stream>>>(xattn, ln_w, ln_b, xnorm);

  // 6. output projection (XCD-chunked swizzle)
  k_gemm_out<<<768, 256, 0, stream>>>(xnorm, wout, out_b, out);
}

// Round 9
// 406.877 us; speedup vs baseline: 1.0662x; 1.0146x over previous
//
#include <hip/hip_runtime.h>
#include <hip/hip_bf16.h>
#include <math.h>

typedef __bf16 bf16_t;
typedef __bf16 bf16x8 __attribute__((ext_vector_type(8)));
typedef __bf16 bf16x4 __attribute__((ext_vector_type(4)));
typedef float f32x4 __attribute__((ext_vector_type(4)));

// ---------- async global->LDS (16B per lane), wave-uniform base + lane*16 ----------
__device__ __forceinline__ void async_ld16(const void* g, void* l) {
  __builtin_amdgcn_global_load_lds(
      (const __attribute__((address_space(1))) unsigned int*)g,
      (__attribute__((address_space(3))) unsigned int*)l, 16, 0, 0);
}

// ---------- problem constants ----------
#define BATCH 2
#define SEQ   8192
#define EMB   768
#define NHEAD 12
#define HD    64
#define TOK   (BATCH*SEQ)          // 16384
#define GATH_PER_B 57344           // sum over heads of L_h = 4*(8192+4096+2048)

// group of head h: g = h>>2 ; L = 8192>>g ; s = 2048<<g ; r = 1<<g ; off = g
__device__ __forceinline__ int headoff(int h) {
  int g = h >> 2;
  int base = (g == 0) ? 0 : ((g == 1) ? 32768 : 49152);
  return base + (h & 3) * (8192 >> g);
}

// exp2 via compiler intrinsic (scores pre-scaled by log2(e) upstream).
__device__ __forceinline__ float fast_exp2(float x) {
#if __has_builtin(__builtin_amdgcn_exp2f)
  return __builtin_amdgcn_exp2f(x);
#else
  return exp2f(x);
#endif
}

// ---------- merged fp32 -> bf16 casts: 5 regions in ONE launch ----------
__global__ __launch_bounds__(256)
void k_cast_all(const float* __restrict__ q, const float* __restrict__ k,
                const float* __restrict__ v, const float* __restrict__ qkvw,
                const float* __restrict__ outw,
                bf16_t* __restrict__ qb, bf16_t* __restrict__ kb,
                bf16_t* __restrict__ vb, bf16_t* __restrict__ wqkv,
                bf16_t* __restrict__ wout) {
  int bid = blockIdx.x;
  const float* src;
  bf16_t* dst;
  int base;
  if (bid < 6144)       { src = q;    dst = qb;   base = bid; }
  else if (bid < 12288) { src = k;    dst = kb;   base = bid - 6144; }
  else if (bid < 18432) { src = v;    dst = vb;   base = bid - 12288; }
  else if (bid < 19296) { src = qkvw; dst = wqkv; base = bid - 18432; }
  else                  { src = outw; dst = wout; base = bid - 19296; }
  int i = (base * 256 + threadIdx.x) * 8;
  float4 a = *(const float4*)(src + i);
  float4 b = *(const float4*)(src + i + 4);
  __attribute__((aligned(16))) bf16_t o[8] = {
      (bf16_t)a.x, (bf16_t)a.y, (bf16_t)a.z, (bf16_t)a.w,
      (bf16_t)b.x, (bf16_t)b.y, (bf16_t)b.z, (bf16_t)b.w};
  *(uint4*)(dst + i) = *(uint4*)o;
}

// ---------- QKV GEMM (bf16 A via async DMA, 2-phase pipelined) + fused gather ----------
// Epilogue: LDS-transpose C-tile so global stores are 16B contiguous (one row-segment
// per thread, one selection computation) instead of 64 scattered 2B stores per thread.
__global__ __launch_bounds__(256, 2)
void k_gemm_qkv(const bf16_t* __restrict__ qb, const bf16_t* __restrict__ kb,
                const bf16_t* __restrict__ vb, const bf16_t* __restrict__ wqkv,
                const float* __restrict__ qkv_bias,
                bf16_t* __restrict__ Qg, bf16_t* __restrict__ Kg, bf16_t* __restrict__ Vb) {
  const int N = 768, K = 768;
  // XCD-chunked bijective swizzle: 2304 blocks = 8 XCDs x 288
  int id = blockIdx.x;
  int wid = (id & 7) * 288 + (id >> 3);
  int z = wid / 768;
  int rem = wid - z * 768;
  int ytile = rem / 6;
  int xtile = rem - ytile * 6;
  int m0 = ytile * 128, n0 = xtile * 128;

  const bf16_t* A = (z == 0) ? qb : (z == 1) ? kb : vb;
  const bf16_t* W = wqkv + (size_t)z * N * K;
  const float* bias = qkv_bias + z * N;

  // LDS pool: As[2][128][32] (8192 elems) + Bs[2][128][32] (8192) during K-loop;
  // overlaid by Cs[128][136] (17408 elems, rows 272B = 16B-aligned) in the epilogue.
  __shared__ __align__(16) bf16_t pool[17408];
  bf16_t (*As)[128][32] = (bf16_t(*)[128][32])pool;
  bf16_t (*Bs)[128][32] = (bf16_t(*)[128][32])(pool + 8192);

  int tid = threadIdx.x;
  int wave = tid >> 6, lane = tid & 63;
  int q = lane >> 4, c = lane & 15;
  int wm = (wave & 1) * 64, wn = (wave >> 1) * 64;

  auto stage = [&](int k0, int bsel) {
#pragma unroll
    for (int it = 0; it < 2; ++it) {
      int ch = tid + it * 256;          // 512 chunks of 16B
      int row = ch >> 2, kb8 = (ch & 3) << 3;
      async_ld16(A + (size_t)(m0 + row) * K + k0 + kb8, &As[bsel][row][kb8]);
      async_ld16(W + (size_t)(n0 + row) * K + k0 + kb8, &Bs[bsel][row][kb8]);
    }
  };

  f32x4 acc[4][4];
#pragma unroll
  for (int i = 0; i < 4; i++)
#pragma unroll
    for (int j = 0; j < 4; j++) acc[i][j] = (f32x4){0.f, 0.f, 0.f, 0.f};

  stage(0, 0);
#pragma unroll 2
  for (int kt = 0; kt < 24; ++kt) {
    int cur = kt & 1;
    __syncthreads();                    // buf[cur] staged; prior reads of buf[cur^1] done
    if (kt + 1 < 24) stage((kt + 1) * 32, cur ^ 1);
    bf16x8 af[4], bfr[4];
#pragma unroll
    for (int mi = 0; mi < 4; mi++) af[mi] = *(const bf16x8*)&As[cur][wm + mi * 16 + c][q * 8];
#pragma unroll
    for (int nj = 0; nj < 4; nj++) bfr[nj] = *(const bf16x8*)&Bs[cur][wn + nj * 16 + c][q * 8];
#pragma unroll
    for (int mi = 0; mi < 4; mi++)
#pragma unroll
      for (int nj = 0; nj < 4; nj++)
        acc[mi][nj] = __builtin_amdgcn_mfma_f32_16x16x32_bf16(af[mi], bfr[nj], acc[mi][nj], 0, 0, 0);
  }

  // ---- epilogue phase 1: acc (+bias, x qscale) -> bf16 into LDS C-tile ----
  __syncthreads();                      // all waves done reading As/Bs
  bf16_t (*Cs)[136] = (bf16_t(*)[136])pool;
  // Q pre-scale folds 1/sqrt(64) AND log2(e) so attn can use raw 2^x
  float qscale = (z == 0) ? 0.125f * 1.44269504088896f : 1.0f;
#pragma unroll
  for (int mi = 0; mi < 4; mi++)
#pragma unroll
    for (int nj = 0; nj < 4; nj++) {
      int col = wn + nj * 16 + c;
      float bi = bias[n0 + col];
#pragma unroll
      for (int rg = 0; rg < 4; rg++) {
        int row = wm + mi * 16 + q * 4 + rg;
        Cs[row][col] = (bf16_t)((acc[mi][nj][rg] + bi) * qscale);
      }
    }
  __syncthreads();

  // ---- epilogue phase 2: one (row, head-half) per thread, 128B contiguous copy ----
  int row = tid >> 1, hh = tid & 1;
  if (z == 2) {
    bf16_t* dp = Vb + (size_t)(m0 + row) * N + n0 + hh * 64;
#pragma unroll
    for (int k2 = 0; k2 < 8; k2++)
      *(uint4*)(dp + k2 * 8) = *(const uint4*)&Cs[row][hh * 64 + k2 * 8];
  } else {
    bf16_t* dstq = (z == 0) ? Qg : Kg;
    int h = (n0 >> 6) + hh;
    int g2 = h >> 2;
    int rm1 = (1 << g2) - 1, sh = 11 + g2;
    int smask = (2048 << g2) - 1;
    int ho = headoff(h);
    int grow = m0 + row, bb = grow >> 13, p = grow & 8191;
    int t = (p & smask) - g2;           // off == g2
    if (t >= 0 && (t & rm1) == 0) {
      int jj = (p >> sh) * 2048 + (t >> g2);
      bf16_t* dp = dstq + (size_t)(bb * GATH_PER_B + ho + jj) * HD;
#pragma unroll
      for (int k2 = 0; k2 < 8; k2++)
        *(uint4*)(dp + k2 * 8) = *(const uint4*)&Cs[row][hh * 64 + k2 * 8];
    }
  }
}

// ---------- output GEMM: fp32 out (2-phase pipelined, XCD-chunked swizzle) ----------
__global__ __launch_bounds__(256, 2)
void k_gemm_out(const bf16_t* __restrict__ A, const bf16_t* __restrict__ W,
                const float* __restrict__ bias, float* __restrict__ C) {
  const int N = 768, K = 768;
  // 768 blocks = 8 XCDs x 96; work ordered (m-panel, n-tile)
  int id = blockIdx.x;
  int wid = (id & 7) * 96 + (id >> 3);
  int ytile = wid / 6;
  int xtile = wid - ytile * 6;
  int m0 = ytile * 128, n0 = xtile * 128;

  __shared__ bf16_t As[2][128][32];
  __shared__ bf16_t Bs[2][128][32];

  int tid = threadIdx.x;
  int wave = tid >> 6, lane = tid & 63;
  int q = lane >> 4, c = lane & 15;
  int wm = (wave & 1) * 64, wn = (wave >> 1) * 64;

  auto stage = [&](int k0, int bsel) {
#pragma unroll
    for (int it = 0; it < 2; ++it) {
      int ch = tid + it * 256;
      int row = ch >> 2, kb8 = (ch & 3) << 3;
      async_ld16(A + (size_t)(m0 + row) * K + k0 + kb8, &As[bsel][row][kb8]);
      async_ld16(W + (size_t)(n0 + row) * K + k0 + kb8, &Bs[bsel][row][kb8]);
    }
  };

  f32x4 acc[4][4];
#pragma unroll
  for (int i = 0; i < 4; i++)
#pragma unroll
    for (int j = 0; j < 4; j++) acc[i][j] = (f32x4){0.f, 0.f, 0.f, 0.f};

  stage(0, 0);
#pragma unroll 2
  for (int kt = 0; kt < 24; ++kt) {
    int cur = kt & 1;
    __syncthreads();
    if (kt + 1 < 24) stage((kt + 1) * 32, cur ^ 1);
    bf16x8 af[4], bfr[4];
#pragma unroll
    for (int mi = 0; mi < 4; mi++) af[mi] = *(const bf16x8*)&As[cur][wm + mi * 16 + c][q * 8];
#pragma unroll
    for (int nj = 0; nj < 4; nj++) bfr[nj] = *(const bf16x8*)&Bs[cur][wn + nj * 16 + c][q * 8];
#pragma unroll
    for (int mi = 0; mi < 4; mi++)
#pragma unroll
      for (int nj = 0; nj < 4; nj++)
        acc[mi][nj] = __builtin_amdgcn_mfma_f32_16x16x32_bf16(af[mi], bfr[nj], acc[mi][nj], 0, 0, 0);
  }
#pragma unroll
  for (int mi = 0; mi < 4; mi++)
#pragma unroll
    for (int nj = 0; nj < 4; nj++)
#pragma unroll
      for (int rg = 0; rg < 4; rg++) {
        int row = m0 + wm + mi * 16 + q * 4 + rg;
        int col = n0 + wn + nj * 16 + c;
        C[(size_t)row * N + col] = acc[mi][nj][rg] + bias[col];
      }
}

// ---------- V gather: Vb [tok][768] -> Vt [head][dim][L], slot-permuted ----------
// compact grid: 896 useful (h, jj0) pairs per batch (no early-return blocks)
__global__ __launch_bounds__(256)
void k_gather_v(const bf16_t* __restrict__ Vb, bf16_t* __restrict__ Vt) {
  int u = blockIdx.x, b = blockIdx.y;
  int h, jj0;
  if (u < 512)      { h = u >> 7;              jj0 = (u & 127) * 64; }
  else if (u < 768) { int w = u - 512; h = 4 + (w >> 6); jj0 = (w & 63) * 64; }
  else              { int w = u - 768; h = 8 + (w >> 5); jj0 = (w & 31) * 64; }
  int g = h >> 2;
  int L = 8192 >> g;
  int s = 2048 << g;
  int hb = b * GATH_PER_B + headoff(h);
  int tid = threadIdx.x;

  __shared__ bf16_t tile[64][72];

#pragma unroll
  for (int it = 0; it < 2; ++it) {
    int ch = tid + it * 256;            // 512 chunks: 64 rows x 8 chunks of 16B
    int rowl = ch >> 3, db = (ch & 7) << 3;
    int jj = jj0 + rowl;
    int p = (jj >> 11) * s + g + ((jj & 2047) << g);
    *(uint4*)&tile[rowl][db] = *(const uint4*)(Vb + ((size_t)(b * SEQ + p)) * EMB + h * HD + db);
  }
  __syncthreads();
  int dim = tid >> 2, sub = tid & 3;
  __attribute__((aligned(16))) bf16_t tmp[16];
#pragma unroll
  for (int sl = 0; sl < 16; sl++) {
    int t = sub * 16 + sl;
    int pos = (t & 3) * 16 + (t >> 2);
    tmp[sl] = tile[pos][dim];
  }
  size_t vdst = ((size_t)hb) * HD + (size_t)dim * L + jj0 + sub * 16;
  *(uint4*)(Vt + vdst) = *(uint4*)&tmp[0];
  *(uint4*)(Vt + vdst + 8) = *(uint4*)&tmp[8];
}

// ---------- flash attention ----------
// Double-buffered K/V staging (80KB LDS, 2 blocks/CU), single barrier per KV tile.
__global__ __launch_bounds__(256, 2)
void k_attn(const bf16_t* __restrict__ Qg, const bf16_t* __restrict__ Kg,
            const bf16_t* __restrict__ Vt, bf16_t* __restrict__ xattn) {
  // block id = qt*56 + seg: all 16 Q-tiles of a segment share an XCD (56 % 8 == 0)
  int u = blockIdx.x;
  int seg = u % 56, qt = u / 56;
  int b = seg / 28, t = seg % 28;
  int g, h, si;
  if (t < 16)      { g = 0; h = t >> 2;              si = t & 3; }
  else if (t < 24) { g = 1; h = 4 + ((t - 16) >> 1); si = (t - 16) & 1; }
  else             { g = 2; h = 8 + (t - 24);        si = 0; }
  int L = 8192 >> g, s = 2048 << g;
  int hb = b * GATH_PER_B + headoff(h);
  int jj0 = si * 2048 + qt * 128;
  int kvbase = si * 2048;

  __shared__ bf16_t Ps[128][64];        // 16KB: P half-tile round-trip; doubles as Q staging
  __shared__ bf16_t Ks[2][128][64];     // 32KB double-buffered
  __shared__ bf16_t Vs[2][64][128];     // 32KB double-buffered ([dim][slot], pre-permuted)

  int tid = threadIdx.x, wave = tid >> 6, lane = tid & 63;
  int q = lane >> 4, c = lane & 15;
  int cx = c & 7;
  int wm = wave * 32;

  auto stageK = [&](int kt, int bsel) {
#pragma unroll
    for (int it = 0; it < 4; ++it) {
      int ch = tid + it * 256;
      int row = ch >> 3, pc = ch & 7, lc = pc ^ (row & 7);
      async_ld16(Kg + ((size_t)(hb + kvbase + kt * 128 + row)) * HD + lc * 8,
                 &Ks[bsel][0][0] + ch * 8);
    }
  };
  auto stageV = [&](int kt, int bsel) {
#pragma unroll
    for (int it = 0; it < 4; ++it) {
      int ch = tid + it * 256;
      int dim = ch >> 4, pc = ch & 15, lc = pc ^ (dim & 7);
      async_ld16(Vt + ((size_t)hb) * HD + (size_t)dim * L + kvbase + kt * 128 + lc * 8,
                 &Vs[bsel][0][0] + ch * 8);
    }
  };

  // stage Q tile [128][64] into Ps area, chunk-swizzled, plus K0/V0 into buffer 0
  bf16_t* Qs = &Ps[0][0];
#pragma unroll
  for (int it = 0; it < 4; ++it) {
    int ch = tid + it * 256;
    int row = ch >> 3, pc = ch & 7, lc = pc ^ (row & 7);
    async_ld16(Qg + ((size_t)(hb + jj0 + row)) * HD + lc * 8, Qs + ch * 8);
  }
  stageK(0, 0);
  stageV(0, 0);
  __syncthreads();                      // Q + K0/V0 staged

  // Q fragments (wave-private Ps rows)
  bf16x8 aq[2][2];
#pragma unroll
  for (int mi = 0; mi < 2; mi++)
#pragma unroll
    for (int kq = 0; kq < 2; kq++) {
      int pch = (kq * 4 + q) ^ cx;
      aq[mi][kq] = *(const bf16x8*)(Qs + (size_t)(wm + mi * 16 + c) * HD + pch * 8);
    }

  float lrow[2][4];
  f32x4 O[2][4];
#pragma unroll
  for (int mi = 0; mi < 2; mi++)
#pragma unroll
    for (int rg = 0; rg < 4; rg++) lrow[mi][rg] = 0.f;
#pragma unroll
  for (int mi = 0; mi < 2; mi++)
#pragma unroll
    for (int vd = 0; vd < 4; vd++) O[mi][vd] = (f32x4){0.f, 0.f, 0.f, 0.f};

#pragma unroll 2
  for (int kt = 0; kt < 16; ++kt) {
    int cur = kt & 1;
    // issue next tile's staging before compute: latency hides under this tile's work
    if (kt < 15) {
      stageK(kt + 1, cur ^ 1);
      stageV(kt + 1, cur ^ 1);
    }

    // S = Q K^T  (Q pre-scaled by log2e/8; scores are in log2 domain)
    f32x4 Sv[2][8];
#pragma unroll
    for (int mi = 0; mi < 2; mi++)
#pragma unroll
      for (int nj = 0; nj < 8; nj++) Sv[mi][nj] = (f32x4){0.f, 0.f, 0.f, 0.f};
#pragma unroll
    for (int kq = 0; kq < 2; kq++) {
      int pch = (kq * 4 + q) ^ cx;
      bf16x8 bk[8];
#pragma unroll
      for (int nj = 0; nj < 8; nj++) bk[nj] = *(const bf16x8*)&Ks[cur][nj * 16 + c][pch * 8];
#pragma unroll
      for (int mi = 0; mi < 2; mi++)
#pragma unroll
        for (int nj = 0; nj < 8; nj++)
          Sv[mi][nj] = __builtin_amdgcn_mfma_f32_16x16x32_bf16(aq[mi][kq], bk[nj], Sv[mi][nj], 0, 0, 0);
    }

    // two KV halves of 64: exp2+pack 4 vals -> ds_write_b64 into Ps[128][64]; then PV
#pragma unroll
    for (int half = 0; half < 2; ++half) {
#pragma unroll
      for (int mi = 0; mi < 2; mi++)
#pragma unroll
        for (int rg = 0; rg < 4; rg++) {
          bf16x4 p4;
          float rs = 0.f;
#pragma unroll
          for (int j = 0; j < 4; j++) {
            float p = fast_exp2(Sv[mi][half * 4 + j][rg]);
            rs += p;
            p4[j] = (bf16_t)p;
          }
          lrow[mi][rg] += rs;
          int row = wm + mi * 16 + q * 4 + rg;
          int u8 = c ^ ((row & 7) << 1);          // 8B-unit swizzle
          *(bf16x4*)((char*)&Ps[row][0] + u8 * 8) = p4;
        }
      // no barrier: Ps rows wm..wm+31 wave-private (DS ops in-order within a wave)
#pragma unroll
      for (int kk2 = 0; kk2 < 2; ++kk2) {
        bf16x8 ap[2], bv[4];
#pragma unroll
        for (int mi = 0; mi < 2; mi++) {
          int u8 = (kk2 * 8 + q * 2) ^ (cx << 1); // even: b128-aligned
          ap[mi] = *(const bf16x8*)((char*)&Ps[wm + mi * 16 + c][0] + u8 * 8);
        }
#pragma unroll
        for (int vd = 0; vd < 4; vd++) {
          int pch = (half * 8 + kk2 * 4 + q) ^ cx;
          bv[vd] = *(const bf16x8*)&Vs[cur][vd * 16 + c][pch * 8];
        }
#pragma unroll
        for (int mi = 0; mi < 2; mi++)
#pragma unroll
          for (int vd = 0; vd < 4; vd++)
            O[mi][vd] = __builtin_amdgcn_mfma_f32_16x16x32_bf16(ap[mi], bv[vd], O[mi][vd], 0, 0, 0);
      }
    }
    // single barrier per tile: drains this iter's stage issues (vmcnt0) and
    // guarantees all waves finished reading buf[cur] before it is re-staged
    __syncthreads();
  }

  // epilogue: l = cross-lane rowsum; out = O / l / 3, scattered to original positions
  const float inv3 = 1.0f / 3.0f;
#pragma unroll
  for (int mi = 0; mi < 2; mi++)
#pragma unroll
    for (int rg = 0; rg < 4; rg++) {
      float l = lrow[mi][rg];
#pragma unroll
      for (int d = 1; d < 16; d <<= 1) l += __shfl_xor(l, d, 64);
      float invl = inv3 / l;
      int jj = jj0 + wm + mi * 16 + q * 4 + rg;
      int p = si * s + g + ((jj & 2047) << g);
      size_t base = ((size_t)(b * SEQ + p)) * EMB + h * HD;
#pragma unroll
      for (int vd = 0; vd < 4; vd++)
        xattn[base + vd * 16 + c] = (bf16_t)(O[mi][vd][rg] * invl);
    }
}

// ---------- LayerNorm (wave per row, 24B contiguous per lane) ----------
__global__ __launch_bounds__(256)
void k_ln(const bf16_t* __restrict__ x, const float* __restrict__ lnw,
          const float* __restrict__ lnb, bf16_t* __restrict__ y) {
  int wave = threadIdx.x >> 6, lane = threadIdx.x & 63;
  int row = blockIdx.x * 4 + wave;
  const bf16_t* xr = x + (size_t)row * EMB + lane * 12;
  bf16x4 v4[3];
#pragma unroll
  for (int j = 0; j < 3; j++) v4[j] = *(const bf16x4*)(xr + j * 4);
  float v[12], s = 0.f, s2 = 0.f;
#pragma unroll
  for (int j = 0; j < 12; j++) {
    v[j] = (float)v4[j >> 2][j & 3];
    s += v[j];
    s2 += v[j] * v[j];
  }
#pragma unroll
  for (int d = 1; d < 64; d <<= 1) { s += __shfl_xor(s, d, 64); s2 += __shfl_xor(s2, d, 64); }
  float mu = s * (1.f / 768.f);
  float var = s2 * (1.f / 768.f) - mu * mu;
  float rstd = rsqrtf(var + 1e-5f);
  const float4* wr = (const float4*)(lnw + lane * 12);
  const float4* br = (const float4*)(lnb + lane * 12);
  bf16_t* yr = y + (size_t)row * EMB + lane * 12;
#pragma unroll
  for (int j = 0; j < 3; j++) {
    float4 w = wr[j], bb = br[j];
    bf16x4 o;
    o[0] = (bf16_t)((v[j * 4 + 0] - mu) * rstd * w.x + bb.x);
    o[1] = (bf16_t)((v[j * 4 + 1] - mu) * rstd * w.y + bb.y);
    o[2] = (bf16_t)((v[j * 4 + 2] - mu) * rstd * w.z + bb.z);
    o[3] = (bf16_t)((v[j * 4 + 3] - mu) * rstd * w.w + bb.w);
    *(bf16x4*)(yr + j * 4) = o;
  }
}

extern "C" void kernel_launch(void* const* d_in, const int* in_sizes, int n_in,
                              void* d_out, int out_size, void* d_ws, size_t ws_size,
                              hipStream_t stream) {
  const float* query = (const float*)d_in[0];
  const float* key   = (const float*)d_in[1];
  const float* value = (const float*)d_in[2];
  const float* qkv_w = (const float*)d_in[3];
  const float* qkv_b = (const float*)d_in[4];
  const float* ln_w  = (const float*)d_in[5];
  const float* ln_b  = (const float*)d_in[6];
  const float* out_w = (const float*)d_in[7];
  const float* out_b = (const float*)d_in[8];
  float* out = (float*)d_out;

  char* ws = (char*)d_ws;
  const size_t A = (size_t)TOK * EMB * 2;   // 25,165,824 bytes per full-tensor slot
  bf16_t* qb    = (bf16_t*)(ws + 0 * A);    // bf16 query  (later: xattn)
  bf16_t* kb    = (bf16_t*)(ws + 1 * A);    // bf16 key    (later: xnorm)
  bf16_t* vb    = (bf16_t*)(ws + 2 * A);    // bf16 value  (later: Vt, 14.7MB)
  bf16_t* Vb    = (bf16_t*)(ws + 3 * A);    // V projected, [tok][768]
  bf16_t* Qg    = (bf16_t*)(ws + 4 * A);    // gathered Q (pre-scaled log2e/8), 14.7MB
  bf16_t* Kg    = (bf16_t*)(ws + 5 * A);    // gathered K, 14.7MB
  bf16_t* wqkv  = (bf16_t*)(ws + 6 * A);
  bf16_t* wout  = (bf16_t*)(ws + 6 * A + (size_t)2304 * 768 * 2);
  // aliases (stream-ordered, lifetimes disjoint):
  bf16_t* Vt    = vb;   // vb dead after qkv GEMM
  bf16_t* xattn = qb;   // qb dead after qkv GEMM
  bf16_t* xnorm = kb;   // kb dead after qkv GEMM

  // 1. ALL fp32 -> bf16 casts in one launch (3 inputs + 2 weights)
  k_cast_all<<<19584, 256, 0, stream>>>(query, key, value, qkv_w, out_w,
                                        qb, kb, vb, wqkv, wout);

  // 2. QKV projection (XCD-chunked swizzle) + fused Q/K dilated-gather epilogue
  k_gemm_qkv<<<2304, 256, 0, stream>>>(qb, kb, vb, wqkv, qkv_b, Qg, Kg, Vb);

  // 3. V gather (transpose + slot-permute), compact grid: 896 useful blocks x 2 batches
  dim3 gg(896, 2);
  k_gather_v<<<gg, 256, 0, stream>>>(Vb, Vt);

  // 4. attention (zero xattn first: non-selected positions must be 0)
  hipMemsetAsync(xattn, 0, A, stream);
  k_attn<<<896, 256, 0, stream>>>(Qg, Kg, Vt, xattn);

  // 5. MAGNETO LN
  k_ln<<<4096, 256, 0, stream>>>(xattn, ln_w, ln_b, xnorm);

  // 6. output projection (XCD-chunked swizzle)
  k_gemm_out<<<768, 256, 0, stream>>>(xnorm, wout, out_b, out);
}

// Round 11
// 405.438 us; speedup vs baseline: 1.0700x; 1.0035x over previous
//
#include <hip/hip_runtime.h>
#include <hip/hip_bf16.h>
#include <math.h>

typedef __bf16 bf16_t;
typedef __bf16 bf16x8 __attribute__((ext_vector_type(8)));
typedef __bf16 bf16x4 __attribute__((ext_vector_type(4)));
typedef float f32x4 __attribute__((ext_vector_type(4)));

// ---------- async global->LDS (16B per lane), wave-uniform base + lane*16 ----------
__device__ __forceinline__ void async_ld16(const void* g, void* l) {
  __builtin_amdgcn_global_load_lds(
      (const __attribute__((address_space(1))) unsigned int*)g,
      (__attribute__((address_space(3))) unsigned int*)l, 16, 0, 0);
}

// ---------- problem constants ----------
#define BATCH 2
#define SEQ   8192
#define EMB   768
#define NHEAD 12
#define HD    64
#define TOK   (BATCH*SEQ)          // 16384
#define GATH_PER_B 57344           // sum over heads of L_h = 4*(8192+4096+2048)

// group of head h: g = h>>2 ; L = 8192>>g ; s = 2048<<g ; r = 1<<g ; off = g
__device__ __forceinline__ int headoff(int h) {
  int g = h >> 2;
  int base = (g == 0) ? 0 : ((g == 1) ? 32768 : 49152);
  return base + (h & 3) * (8192 >> g);
}

// exp2 via compiler intrinsic (scores pre-scaled by log2(e) upstream).
__device__ __forceinline__ float fast_exp2(float x) {
#if __has_builtin(__builtin_amdgcn_exp2f)
  return __builtin_amdgcn_exp2f(x);
#else
  return exp2f(x);
#endif
}

// phase boundary for counted-vmcnt pipelines (m201-proven mechanics):
// compiler-VISIBLE barrier + separate counted waitcnt, fully fenced with
// sched_barrier(0) so nothing is scheduled across (rule #18 class).
#define PIPE_SYNC(N)                                          \
  do {                                                        \
    __builtin_amdgcn_sched_barrier(0);                        \
    asm volatile("s_waitcnt vmcnt(" #N ")" ::: "memory");     \
    __builtin_amdgcn_sched_barrier(0);                        \
    __builtin_amdgcn_s_barrier();                             \
    __builtin_amdgcn_sched_barrier(0);                        \
  } while (0)

// ---------- merged fp32 -> bf16 casts: 5 regions in ONE launch ----------
__global__ __launch_bounds__(256)
void k_cast_all(const float* __restrict__ q, const float* __restrict__ k,
                const float* __restrict__ v, const float* __restrict__ qkvw,
                const float* __restrict__ outw,
                bf16_t* __restrict__ qb, bf16_t* __restrict__ kb,
                bf16_t* __restrict__ vb, bf16_t* __restrict__ wqkv,
                bf16_t* __restrict__ wout) {
  int bid = blockIdx.x;
  const float* src;
  bf16_t* dst;
  int base;
  if (bid < 6144)       { src = q;    dst = qb;   base = bid; }
  else if (bid < 12288) { src = k;    dst = kb;   base = bid - 6144; }
  else if (bid < 18432) { src = v;    dst = vb;   base = bid - 12288; }
  else if (bid < 19296) { src = qkvw; dst = wqkv; base = bid - 18432; }
  else                  { src = outw; dst = wout; base = bid - 19296; }
  int i = (base * 256 + threadIdx.x) * 8;
  float4 a = *(const float4*)(src + i);
  float4 b = *(const float4*)(src + i + 4);
  __attribute__((aligned(16))) bf16_t o[8] = {
      (bf16_t)a.x, (bf16_t)a.y, (bf16_t)a.z, (bf16_t)a.w,
      (bf16_t)b.x, (bf16_t)b.y, (bf16_t)b.z, (bf16_t)b.w};
  *(uint4*)(dst + i) = *(uint4*)o;
}

// ---------- QKV GEMM: 3-buffer 2-deep counted-vmcnt pipeline + fused gather ----------
// Per iter: {vmcnt(4); barrier} -> stage tile kt+2 -> compute tile kt. Each tile's
// 4 loads/wave get ~2 iterations to land. Correctness: per-wave vmcnt(4) = my tile-kt
// loads done (only kt+1's 4 newer remain); compiler-visible barrier makes all waves'
// portions visible; buf (kt+2)%3 was last read at iter kt-1 and is re-staged only
// after iter kt's barrier -> no WAR race. Last iter peeled with vmcnt(0).
__global__ __launch_bounds__(256, 2)
void k_gemm_qkv(const bf16_t* __restrict__ qb, const bf16_t* __restrict__ kb,
                const bf16_t* __restrict__ vb, const bf16_t* __restrict__ wqkv,
                const float* __restrict__ qkv_bias,
                bf16_t* __restrict__ Qg, bf16_t* __restrict__ Kg, bf16_t* __restrict__ Vb) {
  const int N = 768, K = 768;
  // XCD-chunked bijective swizzle: 2304 blocks = 8 XCDs x 288
  int id = blockIdx.x;
  int wid = (id & 7) * 288 + (id >> 3);
  int z = wid / 768;
  int rem = wid - z * 768;
  int ytile = rem / 6;
  int xtile = rem - ytile * 6;
  int m0 = ytile * 128, n0 = xtile * 128;

  const bf16_t* A = (z == 0) ? qb : (z == 1) ? kb : vb;
  const bf16_t* W = wqkv + (size_t)z * N * K;
  const float* bias = qkv_bias + z * N;

  // LDS pool: As[3][128][32] (12288 elems) + Bs[3][128][32] (12288) during K-loop;
  // overlaid by Cs[128][136] (17408 elems) in the epilogue. 48KB.
  __shared__ __align__(16) bf16_t pool[24576];
  bf16_t (*As)[128][32] = (bf16_t(*)[128][32])pool;
  bf16_t (*Bs)[128][32] = (bf16_t(*)[128][32])(pool + 12288);

  int tid = threadIdx.x;
  int wave = tid >> 6, lane = tid & 63;
  int q = lane >> 4, c = lane & 15;
  int wm = (wave & 1) * 64, wn = (wave >> 1) * 64;

  auto stage = [&](int k0, int bsel) {
#pragma unroll
    for (int it = 0; it < 2; ++it) {
      int ch = tid + it * 256;          // 512 chunks of 16B; 4 load-insts/wave total
      int row = ch >> 2, kb8 = (ch & 3) << 3;
      async_ld16(A + (size_t)(m0 + row) * K + k0 + kb8, &As[bsel][row][kb8]);
      async_ld16(W + (size_t)(n0 + row) * K + k0 + kb8, &Bs[bsel][row][kb8]);
    }
  };

  f32x4 acc[4][4];
#pragma unroll
  for (int i = 0; i < 4; i++)
#pragma unroll
    for (int j = 0; j < 4; j++) acc[i][j] = (f32x4){0.f, 0.f, 0.f, 0.f};

  auto compute = [&](int bsel) {
    bf16x8 af[4], bfr[4];
#pragma unroll
    for (int mi = 0; mi < 4; mi++) af[mi] = *(const bf16x8*)&As[bsel][wm + mi * 16 + c][q * 8];
#pragma unroll
    for (int nj = 0; nj < 4; nj++) bfr[nj] = *(const bf16x8*)&Bs[bsel][wn + nj * 16 + c][q * 8];
#pragma unroll
    for (int mi = 0; mi < 4; mi++)
#pragma unroll
      for (int nj = 0; nj < 4; nj++)
        acc[mi][nj] = __builtin_amdgcn_mfma_f32_16x16x32_bf16(af[mi], bfr[nj], acc[mi][nj], 0, 0, 0);
  };

  stage(0, 0);
  stage(32, 1);
#pragma unroll 3
  for (int kt = 0; kt < 23; ++kt) {
    PIPE_SYNC(4);                       // my tile-kt loads done (kt+1's 4 in flight)
    if (kt < 22) stage((kt + 2) * 32, (kt + 2) % 3);
    compute(kt % 3);
  }
  PIPE_SYNC(0);
  compute(23 % 3);

  // ---- epilogue phase 1: acc (+bias, x qscale) -> bf16 into LDS C-tile ----
  __syncthreads();                      // all waves done reading As/Bs
  bf16_t (*Cs)[136] = (bf16_t(*)[136])pool;
  // Q pre-scale folds 1/sqrt(64) AND log2(e) so attn can use raw 2^x
  float qscale = (z == 0) ? 0.125f * 1.44269504088896f : 1.0f;
#pragma unroll
  for (int mi = 0; mi < 4; mi++)
#pragma unroll
    for (int nj = 0; nj < 4; nj++) {
      int col = wn + nj * 16 + c;
      float bi = bias[n0 + col];
#pragma unroll
      for (int rg = 0; rg < 4; rg++) {
        int row = wm + mi * 16 + q * 4 + rg;
        Cs[row][col] = (bf16_t)((acc[mi][nj][rg] + bi) * qscale);
      }
    }
  __syncthreads();

  // ---- epilogue phase 2: one (row, head-half) per thread, 128B contiguous copy ----
  int row = tid >> 1, hh = tid & 1;
  if (z == 2) {
    bf16_t* dp = Vb + (size_t)(m0 + row) * N + n0 + hh * 64;
#pragma unroll
    for (int k2 = 0; k2 < 8; k2++)
      *(uint4*)(dp + k2 * 8) = *(const uint4*)&Cs[row][hh * 64 + k2 * 8];
  } else {
    bf16_t* dstq = (z == 0) ? Qg : Kg;
    int h = (n0 >> 6) + hh;
    int g2 = h >> 2;
    int rm1 = (1 << g2) - 1, sh = 11 + g2;
    int smask = (2048 << g2) - 1;
    int ho = headoff(h);
    int grow = m0 + row, bb = grow >> 13, p = grow & 8191;
    int t = (p & smask) - g2;           // off == g2
    if (t >= 0 && (t & rm1) == 0) {
      int jj = (p >> sh) * 2048 + (t >> g2);
      bf16_t* dp = dstq + (size_t)(bb * GATH_PER_B + ho + jj) * HD;
#pragma unroll
      for (int k2 = 0; k2 < 8; k2++)
        *(uint4*)(dp + k2 * 8) = *(const uint4*)&Cs[row][hh * 64 + k2 * 8];
    }
  }
}

// ---------- output GEMM: fp32 out (3-buffer counted-vmcnt, XCD-chunked swizzle) ----------
__global__ __launch_bounds__(256, 2)
void k_gemm_out(const bf16_t* __restrict__ A, const bf16_t* __restrict__ W,
                const float* __restrict__ bias, float* __restrict__ C) {
  const int N = 768, K = 768;
  // 768 blocks = 8 XCDs x 96; work ordered (m-panel, n-tile)
  int id = blockIdx.x;
  int wid = (id & 7) * 96 + (id >> 3);
  int ytile = wid / 6;
  int xtile = wid - ytile * 6;
  int m0 = ytile * 128, n0 = xtile * 128;

  __shared__ bf16_t As[3][128][32];
  __shared__ bf16_t Bs[3][128][32];

  int tid = threadIdx.x;
  int wave = tid >> 6, lane = tid & 63;
  int q = lane >> 4, c = lane & 15;
  int wm = (wave & 1) * 64, wn = (wave >> 1) * 64;

  auto stage = [&](int k0, int bsel) {
#pragma unroll
    for (int it = 0; it < 2; ++it) {
      int ch = tid + it * 256;
      int row = ch >> 2, kb8 = (ch & 3) << 3;
      async_ld16(A + (size_t)(m0 + row) * K + k0 + kb8, &As[bsel][row][kb8]);
      async_ld16(W + (size_t)(n0 + row) * K + k0 + kb8, &Bs[bsel][row][kb8]);
    }
  };

  f32x4 acc[4][4];
#pragma unroll
  for (int i = 0; i < 4; i++)
#pragma unroll
    for (int j = 0; j < 4; j++) acc[i][j] = (f32x4){0.f, 0.f, 0.f, 0.f};

  auto compute = [&](int bsel) {
    bf16x8 af[4], bfr[4];
#pragma unroll
    for (int mi = 0; mi < 4; mi++) af[mi] = *(const bf16x8*)&As[bsel][wm + mi * 16 + c][q * 8];
#pragma unroll
    for (int nj = 0; nj < 4; nj++) bfr[nj] = *(const bf16x8*)&Bs[bsel][wn + nj * 16 + c][q * 8];
#pragma unroll
    for (int mi = 0; mi < 4; mi++)
#pragma unroll
      for (int nj = 0; nj < 4; nj++)
        acc[mi][nj] = __builtin_amdgcn_mfma_f32_16x16x32_bf16(af[mi], bfr[nj], acc[mi][nj], 0, 0, 0);
  };

  stage(0, 0);
  stage(32, 1);
#pragma unroll 3
  for (int kt = 0; kt < 23; ++kt) {
    PIPE_SYNC(4);
    if (kt < 22) stage((kt + 2) * 32, (kt + 2) % 3);
    compute(kt % 3);
  }
  PIPE_SYNC(0);
  compute(23 % 3);

#pragma unroll
  for (int mi = 0; mi < 4; mi++)
#pragma unroll
    for (int nj = 0; nj < 4; nj++)
#pragma unroll
      for (int rg = 0; rg < 4; rg++) {
        int row = m0 + wm + mi * 16 + q * 4 + rg;
        int col = n0 + wn + nj * 16 + c;
        C[(size_t)row * N + col] = acc[mi][nj][rg] + bias[col];
      }
}

// ---------- V gather: Vb [tok][768] -> Vt [head][dim][L], slot-permuted ----------
// compact grid: 896 useful (h, jj0) pairs per batch (no early-return blocks)
__global__ __launch_bounds__(256)
void k_gather_v(const bf16_t* __restrict__ Vb, bf16_t* __restrict__ Vt) {
  int u = blockIdx.x, b = blockIdx.y;
  int h, jj0;
  if (u < 512)      { h = u >> 7;              jj0 = (u & 127) * 64; }
  else if (u < 768) { int w = u - 512; h = 4 + (w >> 6); jj0 = (w & 63) * 64; }
  else              { int w = u - 768; h = 8 + (w >> 5); jj0 = (w & 31) * 64; }
  int g = h >> 2;
  int L = 8192 >> g;
  int s = 2048 << g;
  int hb = b * GATH_PER_B + headoff(h);
  int tid = threadIdx.x;

  __shared__ bf16_t tile[64][72];

#pragma unroll
  for (int it = 0; it < 2; ++it) {
    int ch = tid + it * 256;            // 512 chunks: 64 rows x 8 chunks of 16B
    int rowl = ch >> 3, db = (ch & 7) << 3;
    int jj = jj0 + rowl;
    int p = (jj >> 11) * s + g + ((jj & 2047) << g);
    *(uint4*)&tile[rowl][db] = *(const uint4*)(Vb + ((size_t)(b * SEQ + p)) * EMB + h * HD + db);
  }
  __syncthreads();
  int dim = tid >> 2, sub = tid & 3;
  __attribute__((aligned(16))) bf16_t tmp[16];
#pragma unroll
  for (int sl = 0; sl < 16; sl++) {
    int t = sub * 16 + sl;
    int pos = (t & 3) * 16 + (t >> 2);
    tmp[sl] = tile[pos][dim];
  }
  size_t vdst = ((size_t)hb) * HD + (size_t)dim * L + jj0 + sub * 16;
  *(uint4*)(Vt + vdst) = *(uint4*)&tmp[0];
  *(uint4*)(Vt + vdst + 8) = *(uint4*)&tmp[8];
}

// ---------- flash attention ----------
// Double-buffered K/V staging (80KB LDS, 2 blocks/CU), single barrier per KV tile.
__global__ __launch_bounds__(256, 2)
void k_attn(const bf16_t* __restrict__ Qg, const bf16_t* __restrict__ Kg,
            const bf16_t* __restrict__ Vt, bf16_t* __restrict__ xattn) {
  // block id = qt*56 + seg: all 16 Q-tiles of a segment share an XCD (56 % 8 == 0)
  int u = blockIdx.x;
  int seg = u % 56, qt = u / 56;
  int b = seg / 28, t = seg % 28;
  int g, h, si;
  if (t < 16)      { g = 0; h = t >> 2;              si = t & 3; }
  else if (t < 24) { g = 1; h = 4 + ((t - 16) >> 1); si = (t - 16) & 1; }
  else             { g = 2; h = 8 + (t - 24);        si = 0; }
  int L = 8192 >> g, s = 2048 << g;
  int hb = b * GATH_PER_B + headoff(h);
  int jj0 = si * 2048 + qt * 128;
  int kvbase = si * 2048;

  __shared__ bf16_t Ps[128][64];        // 16KB: P half-tile round-trip; doubles as Q staging
  __shared__ bf16_t Ks[2][128][64];     // 32KB double-buffered
  __shared__ bf16_t Vs[2][64][128];     // 32KB double-buffered ([dim][slot], pre-permuted)

  int tid = threadIdx.x, wave = tid >> 6, lane = tid & 63;
  int q = lane >> 4, c = lane & 15;
  int cx = c & 7;
  int wm = wave * 32;

  auto stageK = [&](int kt, int bsel) {
#pragma unroll
    for (int it = 0; it < 4; ++it) {
      int ch = tid + it * 256;
      int row = ch >> 3, pc = ch & 7, lc = pc ^ (row & 7);
      async_ld16(Kg + ((size_t)(hb + kvbase + kt * 128 + row)) * HD + lc * 8,
                 &Ks[bsel][0][0] + ch * 8);
    }
  };
  auto stageV = [&](int kt, int bsel) {
#pragma unroll
    for (int it = 0; it < 4; ++it) {
      int ch = tid + it * 256;
      int dim = ch >> 4, pc = ch & 15, lc = pc ^ (dim & 7);
      async_ld16(Vt + ((size_t)hb) * HD + (size_t)dim * L + kvbase + kt * 128 + lc * 8,
                 &Vs[bsel][0][0] + ch * 8);
    }
  };

  // stage Q tile [128][64] into Ps area, chunk-swizzled, plus K0/V0 into buffer 0
  bf16_t* Qs = &Ps[0][0];
#pragma unroll
  for (int it = 0; it < 4; ++it) {
    int ch = tid + it * 256;
    int row = ch >> 3, pc = ch & 7, lc = pc ^ (row & 7);
    async_ld16(Qg + ((size_t)(hb + jj0 + row)) * HD + lc * 8, Qs + ch * 8);
  }
  stageK(0, 0);
  stageV(0, 0);
  __syncthreads();                      // Q + K0/V0 staged

  // Q fragments (wave-private Ps rows)
  bf16x8 aq[2][2];
#pragma unroll
  for (int mi = 0; mi < 2; mi++)
#pragma unroll
    for (int kq = 0; kq < 2; kq++) {
      int pch = (kq * 4 + q) ^ cx;
      aq[mi][kq] = *(const bf16x8*)(Qs + (size_t)(wm + mi * 16 + c) * HD + pch * 8);
    }

  float lrow[2][4];
  f32x4 O[2][4];
#pragma unroll
  for (int mi = 0; mi < 2; mi++)
#pragma unroll
    for (int rg = 0; rg < 4; rg++) lrow[mi][rg] = 0.f;
#pragma unroll
  for (int mi = 0; mi < 2; mi++)
#pragma unroll
    for (int vd = 0; vd < 4; vd++) O[mi][vd] = (f32x4){0.f, 0.f, 0.f, 0.f};

#pragma unroll 2
  for (int kt = 0; kt < 16; ++kt) {
    int cur = kt & 1;
    // issue next tile's staging before compute: latency hides under this tile's work
    if (kt < 15) {
      stageK(kt + 1, cur ^ 1);
      stageV(kt + 1, cur ^ 1);
    }

    // S = Q K^T  (Q pre-scaled by log2e/8; scores are in log2 domain)
    f32x4 Sv[2][8];
#pragma unroll
    for (int mi = 0; mi < 2; mi++)
#pragma unroll
      for (int nj = 0; nj < 8; nj++) Sv[mi][nj] = (f32x4){0.f, 0.f, 0.f, 0.f};
#pragma unroll
    for (int kq = 0; kq < 2; kq++) {
      int pch = (kq * 4 + q) ^ cx;
      bf16x8 bk[8];
#pragma unroll
      for (int nj = 0; nj < 8; nj++) bk[nj] = *(const bf16x8*)&Ks[cur][nj * 16 + c][pch * 8];
#pragma unroll
      for (int mi = 0; mi < 2; mi++)
#pragma unroll
        for (int nj = 0; nj < 8; nj++)
          Sv[mi][nj] = __builtin_amdgcn_mfma_f32_16x16x32_bf16(aq[mi][kq], bk[nj], Sv[mi][nj], 0, 0, 0);
    }

    // two KV halves of 64: exp2+pack 4 vals -> ds_write_b64 into Ps[128][64]; then PV
#pragma unroll
    for (int half = 0; half < 2; ++half) {
#pragma unroll
      for (int mi = 0; mi < 2; mi++)
#pragma unroll
        for (int rg = 0; rg < 4; rg++) {
          bf16x4 p4;
          float rs = 0.f;
#pragma unroll
          for (int j = 0; j < 4; j++) {
            float p = fast_exp2(Sv[mi][half * 4 + j][rg]);
            rs += p;
            p4[j] = (bf16_t)p;
          }
          lrow[mi][rg] += rs;
          int row = wm + mi * 16 + q * 4 + rg;
          int u8 = c ^ ((row & 7) << 1);          // 8B-unit swizzle
          *(bf16x4*)((char*)&Ps[row][0] + u8 * 8) = p4;
        }
      // no barrier: Ps rows wm..wm+31 wave-private (DS ops in-order within a wave)
#pragma unroll
      for (int kk2 = 0; kk2 < 2; ++kk2) {
        bf16x8 ap[2], bv[4];
#pragma unroll
        for (int mi = 0; mi < 2; mi++) {
          int u8 = (kk2 * 8 + q * 2) ^ (cx << 1); // even: b128-aligned
          ap[mi] = *(const bf16x8*)((char*)&Ps[wm + mi * 16 + c][0] + u8 * 8);
        }
#pragma unroll
        for (int vd = 0; vd < 4; vd++) {
          int pch = (half * 8 + kk2 * 4 + q) ^ cx;
          bv[vd] = *(const bf16x8*)&Vs[cur][vd * 16 + c][pch * 8];
        }
#pragma unroll
        for (int mi = 0; mi < 2; mi++)
#pragma unroll
          for (int vd = 0; vd < 4; vd++)
            O[mi][vd] = __builtin_amdgcn_mfma_f32_16x16x32_bf16(ap[mi], bv[vd], O[mi][vd], 0, 0, 0);
      }
    }
    // single barrier per tile: drains this iter's stage issues (vmcnt0) and
    // guarantees all waves finished reading buf[cur] before it is re-staged
    __syncthreads();
  }

  // epilogue: l = cross-lane rowsum; out = O / l / 3, scattered to original positions
  const float inv3 = 1.0f / 3.0f;
#pragma unroll
  for (int mi = 0; mi < 2; mi++)
#pragma unroll
    for (int rg = 0; rg < 4; rg++) {
      float l = lrow[mi][rg];
#pragma unroll
      for (int d = 1; d < 16; d <<= 1) l += __shfl_xor(l, d, 64);
      float invl = inv3 / l;
      int jj = jj0 + wm + mi * 16 + q * 4 + rg;
      int p = si * s + g + ((jj & 2047) << g);
      size_t base = ((size_t)(b * SEQ + p)) * EMB + h * HD;
#pragma unroll
      for (int vd = 0; vd < 4; vd++)
        xattn[base + vd * 16 + c] = (bf16_t)(O[mi][vd][rg] * invl);
    }
}

// ---------- LayerNorm (wave per row, 24B contiguous per lane) ----------
__global__ __launch_bounds__(256)
void k_ln(const bf16_t* __restrict__ x, const float* __restrict__ lnw,
          const float* __restrict__ lnb, bf16_t* __restrict__ y) {
  int wave = threadIdx.x >> 6, lane = threadIdx.x & 63;
  int row = blockIdx.x * 4 + wave;
  const bf16_t* xr = x + (size_t)row * EMB + lane * 12;
  bf16x4 v4[3];
#pragma unroll
  for (int j = 0; j < 3; j++) v4[j] = *(const bf16x4*)(xr + j * 4);
  float v[12], s = 0.f, s2 = 0.f;
#pragma unroll
  for (int j = 0; j < 12; j++) {
    v[j] = (float)v4[j >> 2][j & 3];
    s += v[j];
    s2 += v[j] * v[j];
  }
#pragma unroll
  for (int d = 1; d < 64; d <<= 1) { s += __shfl_xor(s, d, 64); s2 += __shfl_xor(s2, d, 64); }
  float mu = s * (1.f / 768.f);
  float var = s2 * (1.f / 768.f) - mu * mu;
  float rstd = rsqrtf(var + 1e-5f);
  const float4* wr = (const float4*)(lnw + lane * 12);
  const float4* br = (const float4*)(lnb + lane * 12);
  bf16_t* yr = y + (size_t)row * EMB + lane * 12;
#pragma unroll
  for (int j = 0; j < 3; j++) {
    float4 w = wr[j], bb = br[j];
    bf16x4 o;
    o[0] = (bf16_t)((v[j * 4 + 0] - mu) * rstd * w.x + bb.x);
    o[1] = (bf16_t)((v[j * 4 + 1] - mu) * rstd * w.y + bb.y);
    o[2] = (bf16_t)((v[j * 4 + 2] - mu) * rstd * w.z + bb.z);
    o[3] = (bf16_t)((v[j * 4 + 3] - mu) * rstd * w.w + bb.w);
    *(bf16x4*)(yr + j * 4) = o;
  }
}

extern "C" void kernel_launch(void* const* d_in, const int* in_sizes, int n_in,
                              void* d_out, int out_size, void* d_ws, size_t ws_size,
                              hipStream_t stream) {
  const float* query = (const float*)d_in[0];
  const float* key   = (const float*)d_in[1];
  const float* value = (const float*)d_in[2];
  const float* qkv_w = (const float*)d_in[3];
  const float* qkv_b = (const float*)d_in[4];
  const float* ln_w  = (const float*)d_in[5];
  const float* ln_b  = (const float*)d_in[6];
  const float* out_w = (const float*)d_in[7];
  const float* out_b = (const float*)d_in[8];
  float* out = (float*)d_out;

  char* ws = (char*)d_ws;
  const size_t A = (size_t)TOK * EMB * 2;   // 25,165,824 bytes per full-tensor slot
  bf16_t* qb    = (bf16_t*)(ws + 0 * A);    // bf16 query  (later: xattn)
  bf16_t* kb    = (bf16_t*)(ws + 1 * A);    // bf16 key    (later: xnorm)
  bf16_t* vb    = (bf16_t*)(ws + 2 * A);    // bf16 value  (later: Vt, 14.7MB)
  bf16_t* Vb    = (bf16_t*)(ws + 3 * A);    // V projected, [tok][768]
  bf16_t* Qg    = (bf16_t*)(ws + 4 * A);    // gathered Q (pre-scaled log2e/8), 14.7MB
  bf16_t* Kg    = (bf16_t*)(ws + 5 * A);    // gathered K, 14.7MB
  bf16_t* wqkv  = (bf16_t*)(ws + 6 * A);
  bf16_t* wout  = (bf16_t*)(ws + 6 * A + (size_t)2304 * 768 * 2);
  // aliases (stream-ordered, lifetimes disjoint):
  bf16_t* Vt    = vb;   // vb dead after qkv GEMM
  bf16_t* xattn = qb;   // qb dead after qkv GEMM
  bf16_t* xnorm = kb;   // kb dead after qkv GEMM

  // 1. ALL fp32 -> bf16 casts in one launch (3 inputs + 2 weights)
  k_cast_all<<<19584, 256, 0, stream>>>(query, key, value, qkv_w, out_w,
                                        qb, kb, vb, wqkv, wout);

  // 2. QKV projection (counted-vmcnt pipeline) + fused Q/K dilated-gather epilogue
  k_gemm_qkv<<<2304, 256, 0, stream>>>(qb, kb, vb, wqkv, qkv_b, Qg, Kg, Vb);

  // 3. V gather (transpose + slot-permute), compact grid: 896 useful blocks x 2 batches
  dim3 gg(896, 2);
  k_gather_v<<<gg, 256, 0, stream>>>(Vb, Vt);

  // 4. attention (zero xattn first: non-selected positions must be 0)
  hipMemsetAsync(xattn, 0, A, stream);
  k_attn<<<896, 256, 0, stream>>>(Qg, Kg, Vt, xattn);

  // 5. MAGNETO LN
  k_ln<<<4096, 256, 0, stream>>>(xattn, ln_w, ln_b, xnorm);

  // 6. output projection (counted-vmcnt pipeline, XCD-chunked swizzle)
  k_gemm_out<<<768, 256, 0, stream>>>(xnorm, wout, out_b, out);
}